// Round 1
// baseline (1394.417 us; speedup 1.0000x reference)
//
#include <hip/hip_runtime.h>
#include <math.h>

#define NT 4
#define BSZ 4
#define BB 16
#define NS 1024
#define SCH 8
#define KC 32
#define SK 16
#define EPS_COS 1e-10f

// monotone encode/decode so atomicMin on unsigned == float min (handles tiny negatives too)
__device__ __forceinline__ unsigned fenc(float f) {
    unsigned u = __float_as_uint(f);
    return (u & 0x80000000u) ? ~u : (u | 0x80000000u);
}
__device__ __forceinline__ float fdec(unsigned u) {
    unsigned v = (u & 0x80000000u) ? (u & 0x7FFFFFFFu) : ~u;
    return __uint_as_float(v);
}

// Gather x[s][c] = g[b,c,ix[b,s]], y[s][c] = t[b%4,c,iy[b,s]]; also per-sample L2 norms.
__global__ void gather_kernel(const float* __restrict__ g, const float* __restrict__ t,
                              const int* __restrict__ ix, const int* __restrict__ iy,
                              float* __restrict__ X, float* __restrict__ Y,
                              float* __restrict__ xn, float* __restrict__ yn,
                              int C, int n, int b0)
{
    int s = blockIdx.x;
    int bl = blockIdx.y;
    int bg = b0 + bl;
    int tid = threadIdx.x;
    int px = ix[bg * NS + s];
    int py = iy[bg * NS + s];
    const float* grow = g + (size_t)bg * C * n;
    const float* trow = t + (size_t)(bg % NT) * C * n;
    float sx = 0.f, sy = 0.f;
    for (int c = tid; c < C; c += 256) {
        float xv = grow[(size_t)c * n + px];
        float yv = trow[(size_t)c * n + py];
        X[((size_t)bl * NS + s) * C + c] = xv;
        Y[((size_t)bl * NS + s) * C + c] = yv;
        sx = fmaf(xv, xv, sx);
        sy = fmaf(yv, yv, sy);
    }
    __shared__ float red[2][4];
    for (int o = 32; o > 0; o >>= 1) { sx += __shfl_down(sx, o); sy += __shfl_down(sy, o); }
    int wid = tid >> 6, lane = tid & 63;
    if (lane == 0) { red[0][wid] = sx; red[1][wid] = sy; }
    __syncthreads();
    if (tid == 0) {
        xn[bl * NS + s] = sqrtf(red[0][0] + red[0][1] + red[0][2] + red[0][3]);
        yn[bl * NS + s] = sqrtf(red[1][0] + red[1][1] + red[1][2] + red[1][3]);
    }
}

// Partial channel sums over sample chunks (deterministic two-stage reduction).
__global__ void sums_kernel(const float* __restrict__ X, const float* __restrict__ Y,
                            float* __restrict__ sxp, float* __restrict__ syp, int C)
{
    int ch = blockIdx.x;
    int bl = blockIdx.y;
    int tid = threadIdx.x;
    int s_beg = ch * (NS / SCH), s_end = s_beg + (NS / SCH);
    for (int c = tid; c < C; c += 256) {
        float ax = 0.f, ay = 0.f;
        for (int s = s_beg; s < s_end; ++s) {
            ax += X[((size_t)bl * NS + s) * C + c];
            ay += Y[((size_t)bl * NS + s) * C + c];
        }
        sxp[((size_t)bl * SCH + ch) * C + c] = ax;
        syp[((size_t)bl * SCH + ch) * C + c] = ay;
    }
}

__global__ void reduce_sums_kernel(const float* __restrict__ sxp, const float* __restrict__ syp,
                                   float* __restrict__ sx, float* __restrict__ sy, int C)
{
    int bl = blockIdx.x;
    for (int c = threadIdx.x; c < C; c += 256) {
        float ax = 0.f, ay = 0.f;
        for (int ch = 0; ch < SCH; ++ch) {
            ax += sxp[((size_t)bl * SCH + ch) * C + c];
            ay += syp[((size_t)bl * SCH + ch) * C + c];
        }
        sx[bl * C + c] = ax;
        sy[bl * C + c] = ay;
    }
}

// 64x64 tile of the 1024x1024 cosine-distance matrix; running row/col mins via atomicMin.
__global__ __launch_bounds__(256) void cross_kernel(
    const float* __restrict__ X, const float* __restrict__ Y,
    const float* __restrict__ xn, const float* __restrict__ yn,
    unsigned* __restrict__ m1u, unsigned* __restrict__ m2u, int C)
{
    int bl = blockIdx.z;
    int i0 = blockIdx.x * 64, j0 = blockIdx.y * 64;
    int tid = threadIdx.x;
    int tx = tid & 15, ty = tid >> 4;
    __shared__ alignas(16) float xs[KC][68];  // k-major: [k][i], pad keeps 16B row alignment
    __shared__ alignas(16) float ys[KC][68];
    __shared__ unsigned rmin[64], cmin[64];
    __shared__ float xnl[64], ynl[64];
    if (tid < 64) {
        rmin[tid] = 0xFFFFFFFFu;
        cmin[tid] = 0xFFFFFFFFu;
        xnl[tid] = xn[bl * NS + i0 + tid];
        ynl[tid] = yn[bl * NS + j0 + tid];
    }
    float acc[4][4] = {};
    for (int kk = 0; kk < C; kk += KC) {
        __syncthreads();
        for (int idx = tid; idx < 64 * KC; idx += 256) {
            int i = idx >> 5;     // / KC
            int k = idx & 31;     // % KC
            xs[k][i] = X[((size_t)bl * NS + i0 + i) * C + kk + k];
            ys[k][i] = Y[((size_t)bl * NS + j0 + i) * C + kk + k];
        }
        __syncthreads();
        #pragma unroll
        for (int k = 0; k < KC; ++k) {
            float4 xa = *(const float4*)&xs[k][ty * 4];
            float4 yb = *(const float4*)&ys[k][tx * 4];
            float xv[4] = {xa.x, xa.y, xa.z, xa.w};
            float yv[4] = {yb.x, yb.y, yb.z, yb.w};
            #pragma unroll
            for (int a = 0; a < 4; ++a)
                #pragma unroll
                for (int b2 = 0; b2 < 4; ++b2)
                    acc[a][b2] = fmaf(xv[a], yv[b2], acc[a][b2]);
        }
    }
    float xni[4], ynj[4];
    #pragma unroll
    for (int a = 0; a < 4; ++a) { xni[a] = xnl[ty * 4 + a]; ynj[a] = ynl[tx * 4 + a]; }
    float rm[4] = {1e30f, 1e30f, 1e30f, 1e30f};
    float cm[4] = {1e30f, 1e30f, 1e30f, 1e30f};
    #pragma unroll
    for (int a = 0; a < 4; ++a)
        #pragma unroll
        for (int b2 = 0; b2 < 4; ++b2) {
            float d = 1.f - acc[a][b2] / (xni[a] * ynj[b2] + EPS_COS);
            rm[a] = fminf(rm[a], d);
            cm[b2] = fminf(cm[b2], d);
        }
    #pragma unroll
    for (int a = 0; a < 4; ++a) atomicMin(&rmin[ty * 4 + a], fenc(rm[a]));
    #pragma unroll
    for (int b2 = 0; b2 < 4; ++b2) atomicMin(&cmin[tx * 4 + b2], fenc(cm[b2]));
    __syncthreads();
    if (tid < 64) {
        atomicMin(&m2u[bl * NS + i0 + tid], rmin[tid]);  // min over j per i
        atomicMin(&m1u[bl * NS + j0 + tid], cmin[tid]);  // min over i per j
    }
}

// 64x64 tile of the CxC second-moment matrices for X and Y; |cov_x - cov_y| partial sums.
__global__ __launch_bounds__(256) void cov_kernel(
    const float* __restrict__ X, const float* __restrict__ Y,
    const float* __restrict__ sx, const float* __restrict__ sy,
    float* __restrict__ covpart, int C)
{
    int bl = blockIdx.z;
    int c0 = blockIdx.x * 64, d0 = blockIdx.y * 64;
    int tid = threadIdx.x;
    int tx = tid & 15, ty = tid >> 4;
    __shared__ alignas(16) float xc[SK][68], xd[SK][68], yc2[SK][68], yd[SK][68];
    float accX[4][4] = {};
    float accY[4][4] = {};
    for (int ss = 0; ss < NS; ss += SK) {
        __syncthreads();
        for (int idx = tid; idx < SK * 64; idx += 256) {
            int s2 = idx >> 6, cc = idx & 63;
            size_t rowoff = ((size_t)bl * NS + ss + s2) * C;
            xc[s2][cc] = X[rowoff + c0 + cc];
            xd[s2][cc] = X[rowoff + d0 + cc];
            yc2[s2][cc] = Y[rowoff + c0 + cc];
            yd[s2][cc] = Y[rowoff + d0 + cc];
        }
        __syncthreads();
        #pragma unroll
        for (int k = 0; k < SK; ++k) {
            float4 a1 = *(const float4*)&xc[k][ty * 4];
            float4 b1 = *(const float4*)&xd[k][tx * 4];
            float4 a2 = *(const float4*)&yc2[k][ty * 4];
            float4 b2v = *(const float4*)&yd[k][tx * 4];
            float av1[4] = {a1.x, a1.y, a1.z, a1.w}, bv1[4] = {b1.x, b1.y, b1.z, b1.w};
            float av2[4] = {a2.x, a2.y, a2.z, a2.w}, bv2[4] = {b2v.x, b2v.y, b2v.z, b2v.w};
            #pragma unroll
            for (int a = 0; a < 4; ++a)
                #pragma unroll
                for (int b2 = 0; b2 < 4; ++b2) {
                    accX[a][b2] = fmaf(av1[a], bv1[b2], accX[a][b2]);
                    accY[a][b2] = fmaf(av2[a], bv2[b2], accY[a][b2]);
                }
        }
    }
    float scx[4], sdx[4], scy[4], sdy[4];
    #pragma unroll
    for (int a = 0; a < 4; ++a) {
        scx[a] = sx[bl * C + c0 + ty * 4 + a];
        scy[a] = sy[bl * C + c0 + ty * 4 + a];
        sdx[a] = sx[bl * C + d0 + tx * 4 + a];
        sdy[a] = sy[bl * C + d0 + tx * 4 + a];
    }
    const float invNS = 1.f / NS, invNSm1 = 1.f / (NS - 1);
    float tsum = 0.f;
    #pragma unroll
    for (int a = 0; a < 4; ++a)
        #pragma unroll
        for (int b2 = 0; b2 < 4; ++b2) {
            float cx = (accX[a][b2] - scx[a] * sdx[b2] * invNS) * invNSm1;
            float cy = (accY[a][b2] - scy[a] * sdy[b2] * invNS) * invNSm1;
            tsum += fabsf(cx - cy);
        }
    __shared__ float redc[4];
    for (int o = 32; o > 0; o >>= 1) tsum += __shfl_down(tsum, o);
    int wid = tid >> 6, lane = tid & 63;
    if (lane == 0) redc[wid] = tsum;
    __syncthreads();
    if (tid == 0)
        covpart[(size_t)bl * gridDim.x * gridDim.y + blockIdx.y * gridDim.x + blockIdx.x] =
            redc[0] + redc[1] + redc[2] + redc[3];
}

__global__ void finalize_kernel(const unsigned* __restrict__ m1u, const unsigned* __restrict__ m2u,
                                const float* __restrict__ sx, const float* __restrict__ sy,
                                const float* __restrict__ covpart, int ntile2,
                                float* __restrict__ loss_acc, int C, int b0)
{
    int bl = blockIdx.x;
    int tid = threadIdx.x;
    float s1 = 0.f, s2 = 0.f, smu = 0.f, scov = 0.f;
    for (int s = tid; s < NS; s += 256) {
        s1 += fdec(m1u[bl * NS + s]);
        s2 += fdec(m2u[bl * NS + s]);
    }
    for (int c = tid; c < C; c += 256) smu += fabsf(sx[bl * C + c] - sy[bl * C + c]);
    for (int i = tid; i < ntile2; i += 256) scov += covpart[(size_t)bl * ntile2 + i];
    __shared__ float red[4][4];
    for (int o = 32; o > 0; o >>= 1) {
        s1 += __shfl_down(s1, o);
        s2 += __shfl_down(s2, o);
        smu += __shfl_down(smu, o);
        scov += __shfl_down(scov, o);
    }
    int wid = tid >> 6, lane = tid & 63;
    if (lane == 0) { red[0][wid] = s1; red[1][wid] = s2; red[2][wid] = smu; red[3][wid] = scov; }
    __syncthreads();
    if (tid == 0) {
        s1 = red[0][0] + red[0][1] + red[0][2] + red[0][3];
        s2 = red[1][0] + red[1][1] + red[1][2] + red[1][3];
        smu = red[2][0] + red[2][1] + red[2][2] + red[2][3];
        scov = red[3][0] + red[3][1] + red[3][2] + red[3][3];
        float m1m = s1 * (1.f / NS), m2m = s2 * (1.f / NS);
        float mu_diff = smu * (1.f / NS) * (1.f / (float)C);
        float cov_diff = scov / ((float)C * (float)C);
        loss_acc[b0 + bl] += fmaxf(m1m, m2m) + mu_diff + cov_diff;
    }
}

__global__ void out_kernel(const float* __restrict__ loss_acc, float* __restrict__ out)
{
    int t = threadIdx.x;
    if (t < NT) {
        float s = 0.f;
        for (int k = 0; k < BSZ; ++k) s += loss_acc[k * NT + t];
        out[t] = s * (1.f / BSZ);
    }
}

extern "C" void kernel_launch(void* const* d_in, const int* in_sizes, int n_in,
                              void* d_out, int out_size, void* d_ws, size_t ws_size,
                              hipStream_t stream)
{
    // setup_inputs() dict order: t0,g0,ix0,iy0, t1,g1,ix1,iy1, t2,g2,ix2,iy2
    const float* tp[3] = {(const float*)d_in[0], (const float*)d_in[4], (const float*)d_in[8]};
    const float* gp[3] = {(const float*)d_in[1], (const float*)d_in[5], (const float*)d_in[9]};
    const int* ixp[3]  = {(const int*)d_in[2], (const int*)d_in[6], (const int*)d_in[10]};
    const int* iyp[3]  = {(const int*)d_in[3], (const int*)d_in[7], (const int*)d_in[11]};
    const int Cs[3] = {128, 256, 512};
    const int Sp[3] = {128, 64, 32};

    float* out = (float*)d_out;
    char* ws = (char*)d_ws;
    float* loss_acc = (float*)ws;
    size_t base = 256;
    hipMemsetAsync(loss_acc, 0, BB * sizeof(float), stream);

    for (int l = 0; l < 3; ++l) {
        int C = Cs[l];
        int n = Sp[l] * Sp[l];
        int tc = C / 64;
        int ntile2 = tc * tc;
        size_t per_b = (size_t)2 * NS * C * 4   // X, Y
                     + (size_t)2 * NS * 4       // xn, yn
                     + (size_t)2 * SCH * C * 4  // sxp, syp
                     + (size_t)2 * C * 4        // sx, sy
                     + (size_t)2 * NS * 4       // m1u, m2u
                     + (size_t)ntile2 * 4;      // covpart
        size_t avail = (ws_size > base) ? ws_size - base : 0;
        int G = (int)(avail / per_b);
        if (G > BB) G = BB;
        if (G < 1) G = 1;

        for (int b0 = 0; b0 < BB; b0 += G) {
            int nb = (BB - b0 < G) ? (BB - b0) : G;
            char* p = ws + base;
            float* X = (float*)p;   p += (size_t)nb * NS * C * 4;
            float* Y = (float*)p;   p += (size_t)nb * NS * C * 4;
            float* xn = (float*)p;  p += (size_t)nb * NS * 4;
            float* yn = (float*)p;  p += (size_t)nb * NS * 4;
            float* sxp = (float*)p; p += (size_t)nb * SCH * C * 4;
            float* syp = (float*)p; p += (size_t)nb * SCH * C * 4;
            float* sx = (float*)p;  p += (size_t)nb * C * 4;
            float* sy = (float*)p;  p += (size_t)nb * C * 4;
            unsigned* m1u = (unsigned*)p; p += (size_t)nb * NS * 4;
            unsigned* m2u = (unsigned*)p; p += (size_t)nb * NS * 4;
            float* covpart = (float*)p;   p += (size_t)nb * ntile2 * 4;

            gather_kernel<<<dim3(NS, nb), 256, 0, stream>>>(gp[l], tp[l], ixp[l], iyp[l],
                                                            X, Y, xn, yn, C, n, b0);
            sums_kernel<<<dim3(SCH, nb), 256, 0, stream>>>(X, Y, sxp, syp, C);
            reduce_sums_kernel<<<nb, 256, 0, stream>>>(sxp, syp, sx, sy, C);
            hipMemsetAsync(m1u, 0xFF, (size_t)nb * NS * 4, stream);
            hipMemsetAsync(m2u, 0xFF, (size_t)nb * NS * 4, stream);
            cross_kernel<<<dim3(16, 16, nb), 256, 0, stream>>>(X, Y, xn, yn, m1u, m2u, C);
            cov_kernel<<<dim3(tc, tc, nb), 256, 0, stream>>>(X, Y, sx, sy, covpart, C);
            finalize_kernel<<<nb, 256, 0, stream>>>(m1u, m2u, sx, sy, covpart, ntile2,
                                                    loss_acc, C, b0);
        }
    }
    out_kernel<<<1, 64, 0, stream>>>(loss_acc, out);
}

// Round 2
// 640.053 us; speedup vs baseline: 2.1786x; 2.1786x over previous
//
#include <hip/hip_runtime.h>
#include <math.h>

#define NT 4
#define BSZ 4
#define BB 16
#define NS 1024

typedef unsigned short u16;
typedef __attribute__((ext_vector_type(8))) short bf16x8;
typedef __attribute__((ext_vector_type(4))) float f32x4;

// monotone encode/decode so atomicMin on unsigned == float min
__device__ __forceinline__ unsigned fenc(float f) {
    unsigned u = __float_as_uint(f);
    return (u & 0x80000000u) ? ~u : (u | 0x80000000u);
}
__device__ __forceinline__ float fdec(unsigned u) {
    unsigned v = (u & 0x80000000u) ? (u & 0x7FFFFFFFu) : ~u;
    return __uint_as_float(v);
}
__device__ __forceinline__ u16 f2bf(float f) {  // RNE
    unsigned u = __float_as_uint(f);
    unsigned r = u + 0x7FFFu + ((u >> 16) & 1u);
    return (u16)(r >> 16);
}
__device__ __forceinline__ float bf2f(u16 h) {
    return __uint_as_float((unsigned)h << 16);
}

// Gather into channel-major bf16: Xt[bl][c][s] = g[bg][c][ix[bg][s]] (coalesced writes,
// g-row reads hit L1/L2 since one row is reused for all 1024 samples).
__global__ void gather_t(const float* __restrict__ g, const float* __restrict__ t,
                         const int* __restrict__ ix, const int* __restrict__ iy,
                         u16* __restrict__ Xt, u16* __restrict__ Yt,
                         int C, int n, int b0)
{
    int c = blockIdx.x, bl = blockIdx.y, bg = b0 + bl;
    const float* grow = g + ((size_t)bg * C + c) * n;
    const float* trow = t + ((size_t)(bg % NT) * C + c) * n;
    const int* ixr = ix + bg * NS;
    const int* iyr = iy + bg * NS;
    u16* xo = Xt + ((size_t)bl * C + c) * NS;
    u16* yo = Yt + ((size_t)bl * C + c) * NS;
    for (int s = threadIdx.x; s < NS; s += 256) {
        xo[s] = f2bf(grow[ixr[s]]);
        yo[s] = f2bf(trow[iyr[s]]);
    }
}

// Per-sample L2 norms from channel-major layout (coalesced across s, fixed-order loop).
__global__ void colnorm(const u16* __restrict__ Xt, const u16* __restrict__ Yt,
                        float* __restrict__ xn, float* __restrict__ yn, int C)
{
    int bl = blockIdx.y;
    int s = blockIdx.x * 256 + threadIdx.x;
    size_t base = (size_t)bl * C * NS + s;
    float ax = 0.f, ay = 0.f;
    for (int c = 0; c < C; ++c) {
        float xv = bf2f(Xt[base + (size_t)c * NS]);
        float yv = bf2f(Yt[base + (size_t)c * NS]);
        ax = fmaf(xv, xv, ax);
        ay = fmaf(yv, yv, ay);
    }
    xn[bl * NS + s] = sqrtf(ax);
    yn[bl * NS + s] = sqrtf(ay);
}

// 64x64 tile transpose: Zn[s][c] = Zt[c][s] / zn[s]  (bf16 out, sample-major for cross GEMM)
__global__ void transpose_norm(const u16* __restrict__ Zt, const float* __restrict__ zn,
                               u16* __restrict__ Zn, int C)
{
    int bl = blockIdx.z;
    int c0 = blockIdx.x * 64, s0 = blockIdx.y * 64;
    __shared__ __align__(16) u16 T[64][72];
    int tid = threadIdx.x;
    #pragma unroll
    for (int rep = 0; rep < 2; ++rep) {
        int q = tid + rep * 256;
        int rr = q >> 3, seg = q & 7;
        *(float4*)&T[rr][seg * 8] =
            *(const float4*)&Zt[((size_t)bl * C + c0 + rr) * NS + s0 + seg * 8];
    }
    __syncthreads();
    #pragma unroll
    for (int rep = 0; rep < 2; ++rep) {
        int q = tid + rep * 256;
        int sr = q >> 3, cs = q & 7;
        float inv = 1.0f / zn[bl * NS + s0 + sr];
        __align__(16) u16 tmp[8];
        #pragma unroll
        for (int e = 0; e < 8; ++e) tmp[e] = f2bf(bf2f(T[cs * 8 + e][sr]) * inv);
        *(float4*)&Zn[((size_t)bl * NS + s0 + sr) * C + c0 + cs * 8] = *(float4*)tmp;
    }
}

// Channel sums (warp per channel, coalesced over s, deterministic shuffle tree).
__global__ void chansum(const u16* __restrict__ Xt, const u16* __restrict__ Yt,
                        float* __restrict__ sx, float* __restrict__ sy, int C)
{
    int bl = blockIdx.y;
    int c = blockIdx.x * 4 + (threadIdx.x >> 6);
    int lane = threadIdx.x & 63;
    const u16* xb = Xt + ((size_t)bl * C + c) * NS;
    const u16* yb = Yt + ((size_t)bl * C + c) * NS;
    float ax = 0.f, ay = 0.f;
    for (int s = lane; s < NS; s += 64) { ax += bf2f(xb[s]); ay += bf2f(yb[s]); }
    for (int o = 32; o > 0; o >>= 1) { ax += __shfl_down(ax, o); ay += __shfl_down(ay, o); }
    if (lane == 0) { sx[bl * C + c] = ax; sy[bl * C + c] = ay; }
}

// 128x128 MFMA tile of cos-dist = 1 - Xn.Yn^T; fused row/col min epilogue.
__global__ __launch_bounds__(256) void cross_mfma(
    const u16* __restrict__ Xn, const u16* __restrict__ Yn,
    unsigned* __restrict__ m1u, unsigned* __restrict__ m2u, int C)
{
    int bl = blockIdx.z;
    int i0 = blockIdx.x * 128, j0 = blockIdx.y * 128;
    __shared__ __align__(16) u16 As[128][40], Bs[128][40];  // pad 32->40 (80B rows, 16B-aligned)
    int tid = threadIdx.x;
    int w = tid >> 6, lane = tid & 63;
    int wr = w >> 1, wc = w & 1;
    int q = lane >> 4, r = lane & 15;
    const u16* Xb = Xn + ((size_t)bl * NS + i0) * C;
    const u16* Yb = Yn + ((size_t)bl * NS + j0) * C;
    f32x4 acc[4][4];
    #pragma unroll
    for (int m = 0; m < 4; ++m)
        #pragma unroll
        for (int nn = 0; nn < 4; ++nn) acc[m][nn] = (f32x4){0.f, 0.f, 0.f, 0.f};

    for (int kk = 0; kk < C; kk += 32) {
        __syncthreads();
        #pragma unroll
        for (int rep = 0; rep < 2; ++rep) {
            int qid = tid + rep * 256;
            int row = qid >> 2, seg = qid & 3;
            size_t off = (size_t)row * C + kk + seg * 8;
            *(float4*)&As[row][seg * 8] = *(const float4*)&Xb[off];
            *(float4*)&Bs[row][seg * 8] = *(const float4*)&Yb[off];
        }
        __syncthreads();
        bf16x8 a[4], b[4];
        #pragma unroll
        for (int m = 0; m < 4; ++m)
            a[m] = *(const bf16x8*)&As[wr * 64 + m * 16 + r][q * 8];
        #pragma unroll
        for (int nn = 0; nn < 4; ++nn)
            b[nn] = *(const bf16x8*)&Bs[wc * 64 + nn * 16 + r][q * 8];
        #pragma unroll
        for (int m = 0; m < 4; ++m)
            #pragma unroll
            for (int nn = 0; nn < 4; ++nn)
                acc[m][nn] = __builtin_amdgcn_mfma_f32_16x16x32_bf16(a[m], b[nn], acc[m][nn], 0, 0, 0);
    }

    // dist = 1 - acc.  Row-min (over j) and col-min (over i).
    float rm[4][4];   // per (m, reg): min over nn + later over lanes r
    float cm[4];      // per nn: min over m, reg + later over lane quarters
    #pragma unroll
    for (int m = 0; m < 4; ++m)
        #pragma unroll
        for (int reg = 0; reg < 4; ++reg) rm[m][reg] = 1e30f;
    #pragma unroll
    for (int nn = 0; nn < 4; ++nn) cm[nn] = 1e30f;
    #pragma unroll
    for (int m = 0; m < 4; ++m)
        #pragma unroll
        for (int nn = 0; nn < 4; ++nn)
            #pragma unroll
            for (int reg = 0; reg < 4; ++reg) {
                float d = 1.f - acc[m][nn][reg];
                rm[m][reg] = fminf(rm[m][reg], d);
                cm[nn] = fminf(cm[nn], d);
            }
    // row-min: reduce over the 16 lanes (r) of the quarter
    #pragma unroll
    for (int m = 0; m < 4; ++m)
        #pragma unroll
        for (int reg = 0; reg < 4; ++reg) {
            float v = rm[m][reg];
            v = fminf(v, __shfl_xor(v, 1));
            v = fminf(v, __shfl_xor(v, 2));
            v = fminf(v, __shfl_xor(v, 4));
            v = fminf(v, __shfl_xor(v, 8));
            rm[m][reg] = v;
        }
    if (r == 0) {
        #pragma unroll
        for (int m = 0; m < 4; ++m)
            #pragma unroll
            for (int reg = 0; reg < 4; ++reg) {
                int i = i0 + wr * 64 + m * 16 + q * 4 + reg;
                atomicMin(&m2u[bl * NS + i], fenc(rm[m][reg]));
            }
    }
    // col-min: reduce across quarters (q)
    #pragma unroll
    for (int nn = 0; nn < 4; ++nn) {
        float v = cm[nn];
        v = fminf(v, __shfl_xor(v, 16));
        v = fminf(v, __shfl_xor(v, 32));
        cm[nn] = v;
    }
    if (q == 0) {
        #pragma unroll
        for (int nn = 0; nn < 4; ++nn) {
            int j = j0 + wc * 64 + nn * 16 + r;
            atomicMin(&m1u[bl * NS + j], fenc(cm[nn]));
        }
    }
}

// Dual 128x128 MFMA tile of Sxx and Syy (K = 1024 samples, channel-major operands).
// Upper-triangle tiles only; off-diagonal tiles weighted 2x (cov matrices are symmetric).
__global__ __launch_bounds__(256) void cov_mfma(
    const u16* __restrict__ Xt, const u16* __restrict__ Yt,
    const float* __restrict__ sx, const float* __restrict__ sy,
    float* __restrict__ covpart, int C, int ntri)
{
    int bl = blockIdx.y;
    int u = blockIdx.x;
    int ty = 0;
    while ((ty + 1) * (ty + 2) / 2 <= u) ++ty;
    int tx = u - ty * (ty + 1) / 2;
    int c0 = ty * 128, d0 = tx * 128;
    float wgt = (tx == ty) ? 1.f : 2.f;

    __shared__ __align__(16) u16 As[128][40], Bs[128][40], Cs2[128][40], Ds[128][40];
    int tid = threadIdx.x;
    int w = tid >> 6, lane = tid & 63;
    int wr = w >> 1, wc = w & 1;
    int q = lane >> 4, r = lane & 15;
    const u16* Xc = Xt + ((size_t)bl * C + c0) * NS;
    const u16* Xd = Xt + ((size_t)bl * C + d0) * NS;
    const u16* Yc = Yt + ((size_t)bl * C + c0) * NS;
    const u16* Yd = Yt + ((size_t)bl * C + d0) * NS;

    f32x4 accX[4][4], accY[4][4];
    #pragma unroll
    for (int m = 0; m < 4; ++m)
        #pragma unroll
        for (int nn = 0; nn < 4; ++nn) {
            accX[m][nn] = (f32x4){0.f, 0.f, 0.f, 0.f};
            accY[m][nn] = (f32x4){0.f, 0.f, 0.f, 0.f};
        }

    for (int ss = 0; ss < NS; ss += 32) {
        __syncthreads();
        #pragma unroll
        for (int rep = 0; rep < 2; ++rep) {
            int qid = tid + rep * 256;
            int row = qid >> 2, seg = qid & 3;
            size_t off = (size_t)row * NS + ss + seg * 8;
            *(float4*)&As[row][seg * 8]  = *(const float4*)&Xc[off];
            *(float4*)&Bs[row][seg * 8]  = *(const float4*)&Xd[off];
            *(float4*)&Cs2[row][seg * 8] = *(const float4*)&Yc[off];
            *(float4*)&Ds[row][seg * 8]  = *(const float4*)&Yd[off];
        }
        __syncthreads();
        {
            bf16x8 a[4], b[4];
            #pragma unroll
            for (int m = 0; m < 4; ++m) a[m] = *(const bf16x8*)&As[wr * 64 + m * 16 + r][q * 8];
            #pragma unroll
            for (int nn = 0; nn < 4; ++nn) b[nn] = *(const bf16x8*)&Bs[wc * 64 + nn * 16 + r][q * 8];
            #pragma unroll
            for (int m = 0; m < 4; ++m)
                #pragma unroll
                for (int nn = 0; nn < 4; ++nn)
                    accX[m][nn] = __builtin_amdgcn_mfma_f32_16x16x32_bf16(a[m], b[nn], accX[m][nn], 0, 0, 0);
        }
        {
            bf16x8 a[4], b[4];
            #pragma unroll
            for (int m = 0; m < 4; ++m) a[m] = *(const bf16x8*)&Cs2[wr * 64 + m * 16 + r][q * 8];
            #pragma unroll
            for (int nn = 0; nn < 4; ++nn) b[nn] = *(const bf16x8*)&Ds[wc * 64 + nn * 16 + r][q * 8];
            #pragma unroll
            for (int m = 0; m < 4; ++m)
                #pragma unroll
                for (int nn = 0; nn < 4; ++nn)
                    accY[m][nn] = __builtin_amdgcn_mfma_f32_16x16x32_bf16(a[m], b[nn], accY[m][nn], 0, 0, 0);
        }
    }

    // epilogue: |cov_x - cov_y| with rank-1 mean correction
    float scxv[4][4], scyv[4][4], sdxv[4], sdyv[4];
    #pragma unroll
    for (int m = 0; m < 4; ++m)
        #pragma unroll
        for (int reg = 0; reg < 4; ++reg) {
            int c = c0 + wr * 64 + m * 16 + q * 4 + reg;
            scxv[m][reg] = sx[bl * C + c];
            scyv[m][reg] = sy[bl * C + c];
        }
    #pragma unroll
    for (int nn = 0; nn < 4; ++nn) {
        int d = d0 + wc * 64 + nn * 16 + r;
        sdxv[nn] = sx[bl * C + d];
        sdyv[nn] = sy[bl * C + d];
    }
    const float invNS = 1.f / NS, invNSm1 = 1.f / (NS - 1);
    float tsum = 0.f;
    #pragma unroll
    for (int m = 0; m < 4; ++m)
        #pragma unroll
        for (int nn = 0; nn < 4; ++nn)
            #pragma unroll
            for (int reg = 0; reg < 4; ++reg) {
                float cx = (accX[m][nn][reg] - scxv[m][reg] * sdxv[nn] * invNS) * invNSm1;
                float cy = (accY[m][nn][reg] - scyv[m][reg] * sdyv[nn] * invNS) * invNSm1;
                tsum += fabsf(cx - cy);
            }
    tsum *= wgt;
    __shared__ float redc[4];
    for (int o = 32; o > 0; o >>= 1) tsum += __shfl_down(tsum, o);
    if (lane == 0) redc[w] = tsum;
    __syncthreads();
    if (tid == 0)
        covpart[(size_t)bl * ntri + u] = redc[0] + redc[1] + redc[2] + redc[3];
}

__global__ void finalize_kernel(const unsigned* __restrict__ m1u, const unsigned* __restrict__ m2u,
                                const float* __restrict__ sx, const float* __restrict__ sy,
                                const float* __restrict__ covpart, int ntri,
                                float* __restrict__ loss_acc, int C, int b0)
{
    int bl = blockIdx.x;
    int tid = threadIdx.x;
    float s1 = 0.f, s2 = 0.f, smu = 0.f, scov = 0.f;
    for (int s = tid; s < NS; s += 256) {
        s1 += fdec(m1u[bl * NS + s]);
        s2 += fdec(m2u[bl * NS + s]);
    }
    for (int c = tid; c < C; c += 256) smu += fabsf(sx[bl * C + c] - sy[bl * C + c]);
    for (int i = tid; i < ntri; i += 256) scov += covpart[(size_t)bl * ntri + i];
    __shared__ float red[4][4];
    for (int o = 32; o > 0; o >>= 1) {
        s1 += __shfl_down(s1, o);
        s2 += __shfl_down(s2, o);
        smu += __shfl_down(smu, o);
        scov += __shfl_down(scov, o);
    }
    int wid = tid >> 6, lane = tid & 63;
    if (lane == 0) { red[0][wid] = s1; red[1][wid] = s2; red[2][wid] = smu; red[3][wid] = scov; }
    __syncthreads();
    if (tid == 0) {
        s1 = red[0][0] + red[0][1] + red[0][2] + red[0][3];
        s2 = red[1][0] + red[1][1] + red[1][2] + red[1][3];
        smu = red[2][0] + red[2][1] + red[2][2] + red[2][3];
        scov = red[3][0] + red[3][1] + red[3][2] + red[3][3];
        float m1m = s1 * (1.f / NS), m2m = s2 * (1.f / NS);
        float mu_diff = smu * (1.f / NS) * (1.f / (float)C);
        float cov_diff = scov * (1.f / NS) /* placeholder no */;
        cov_diff = scov / ((float)C * (float)C);
        loss_acc[b0 + bl] += fmaxf(m1m, m2m) + mu_diff + cov_diff;
    }
}

__global__ void out_kernel(const float* __restrict__ loss_acc, float* __restrict__ out)
{
    int t = threadIdx.x;
    if (t < NT) {
        float s = 0.f;
        for (int k = 0; k < BSZ; ++k) s += loss_acc[k * NT + t];
        out[t] = s * (1.f / BSZ);
    }
}

static inline size_t alignup(size_t v) { return (v + 255) & ~(size_t)255; }

extern "C" void kernel_launch(void* const* d_in, const int* in_sizes, int n_in,
                              void* d_out, int out_size, void* d_ws, size_t ws_size,
                              hipStream_t stream)
{
    const float* tp[3] = {(const float*)d_in[0], (const float*)d_in[4], (const float*)d_in[8]};
    const float* gp[3] = {(const float*)d_in[1], (const float*)d_in[5], (const float*)d_in[9]};
    const int* ixp[3]  = {(const int*)d_in[2], (const int*)d_in[6], (const int*)d_in[10]};
    const int* iyp[3]  = {(const int*)d_in[3], (const int*)d_in[7], (const int*)d_in[11]};
    const int Cs[3] = {128, 256, 512};
    const int Sp[3] = {128, 64, 32};

    float* out = (float*)d_out;
    char* ws = (char*)d_ws;
    float* loss_acc = (float*)ws;
    size_t base = 256;
    hipMemsetAsync(loss_acc, 0, BB * sizeof(float), stream);

    for (int l = 0; l < 3; ++l) {
        int C = Cs[l];
        int n = Sp[l] * Sp[l];
        int tc = C / 128;
        int ntri = tc * (tc + 1) / 2;
        size_t szZ = alignup((size_t)NS * C * 2);
        size_t per_b = 4 * szZ                      // Xt, Yt, Xn, Yn
                     + 2 * alignup(NS * 4)          // xn, yn
                     + 2 * alignup(C * 4)           // sx, sy
                     + 2 * alignup(NS * 4)          // m1u, m2u
                     + alignup(ntri * 4);           // covpart
        size_t avail = (ws_size > base) ? ws_size - base : 0;
        int G = (int)(avail / per_b);
        if (G > BB) G = BB;
        if (G < 1) G = 1;

        for (int b0 = 0; b0 < BB; b0 += G) {
            int nb = (BB - b0 < G) ? (BB - b0) : G;
            char* p = ws + base;
            u16* Xt = (u16*)p;  p += nb * szZ;
            u16* Yt = (u16*)p;  p += nb * szZ;
            u16* Xn = (u16*)p;  p += nb * szZ;
            u16* Yn = (u16*)p;  p += nb * szZ;
            float* xn = (float*)p; p += nb * alignup(NS * 4);
            float* yn = (float*)p; p += nb * alignup(NS * 4);
            float* sx = (float*)p; p += nb * alignup(C * 4);
            float* sy = (float*)p; p += nb * alignup(C * 4);
            unsigned* m1u = (unsigned*)p; p += nb * alignup(NS * 4);
            unsigned* m2u = (unsigned*)p; p += nb * alignup(NS * 4);
            float* covpart = (float*)p;   p += nb * alignup(ntri * 4);

            gather_t<<<dim3(C, nb), 256, 0, stream>>>(gp[l], tp[l], ixp[l], iyp[l],
                                                      Xt, Yt, C, n, b0);
            colnorm<<<dim3(NS / 256, nb), 256, 0, stream>>>(Xt, Yt, xn, yn, C);
            transpose_norm<<<dim3(C / 64, NS / 64, nb), 256, 0, stream>>>(Xt, xn, Xn, C);
            transpose_norm<<<dim3(C / 64, NS / 64, nb), 256, 0, stream>>>(Yt, yn, Yn, C);
            chansum<<<dim3(C / 4, nb), 256, 0, stream>>>(Xt, Yt, sx, sy, C);
            hipMemsetAsync(m1u, 0xFF, (size_t)nb * alignup(NS * 4), stream);
            hipMemsetAsync(m2u, 0xFF, (size_t)nb * alignup(NS * 4), stream);
            cross_mfma<<<dim3(NS / 128, NS / 128, nb), 256, 0, stream>>>(Xn, Yn, m1u, m2u, C);
            cov_mfma<<<dim3(ntri, nb), 256, 0, stream>>>(Xt, Yt, sx, sy, covpart, C, ntri);
            finalize_kernel<<<nb, 256, 0, stream>>>(m1u, m2u, sx, sy, covpart, ntri,
                                                    loss_acc, C, b0);
        }
    }
    out_kernel<<<1, 64, 0, stream>>>(loss_acc, out);
}

// Round 3
// 426.040 us; speedup vs baseline: 3.2730x; 1.5023x over previous
//
#include <hip/hip_runtime.h>
#include <math.h>

#define NT 4
#define BSZ 4
#define BB 16
#define NS 1024
#define CCH 32

typedef unsigned short u16;
typedef __attribute__((ext_vector_type(8))) short bf16x8;
typedef __attribute__((ext_vector_type(4))) float f32x4;

// monotone encode/decode so atomicMin on unsigned == float min
__device__ __forceinline__ unsigned fenc(float f) {
    unsigned u = __float_as_uint(f);
    return (u & 0x80000000u) ? ~u : (u | 0x80000000u);
}
__device__ __forceinline__ float fdec(unsigned u) {
    unsigned v = (u & 0x80000000u) ? (u & 0x7FFFFFFFu) : ~u;
    return __uint_as_float(v);
}
__device__ __forceinline__ u16 f2bf(float f) {  // RNE
    unsigned u = __float_as_uint(f);
    unsigned r = u + 0x7FFFu + ((u >> 16) & 1u);
    return (u16)(r >> 16);
}
__device__ __forceinline__ float bf2f(u16 h) {
    return __uint_as_float((unsigned)h << 16);
}

// Gather into channel-major bf16: Xt[bl][c][s] = g[bg][c][ix[bg][s]]
__global__ void gather_t(const float* __restrict__ g, const float* __restrict__ t,
                         const int* __restrict__ ix, const int* __restrict__ iy,
                         u16* __restrict__ Xt, u16* __restrict__ Yt,
                         int C, int n, int b0)
{
    int c = blockIdx.x, bl = blockIdx.y, bg = b0 + bl;
    const float* grow = g + ((size_t)bg * C + c) * n;
    const float* trow = t + ((size_t)(bg % NT) * C + c) * n;
    const int* ixr = ix + bg * NS;
    const int* iyr = iy + bg * NS;
    u16* xo = Xt + ((size_t)bl * C + c) * NS;
    u16* yo = Yt + ((size_t)bl * C + c) * NS;
    for (int s = threadIdx.x; s < NS; s += 256) {
        xo[s] = f2bf(grow[ixr[s]]);
        yo[s] = f2bf(trow[iyr[s]]);
    }
}

// Partial sums of squares over CCH-channel chunks; 2 samples/thread via uint loads.
__global__ void colnorm_part(const u16* __restrict__ Xt, const u16* __restrict__ Yt,
                             float* __restrict__ xp, float* __restrict__ yp, int C)
{
    int bl = blockIdx.z;
    int chunk = blockIdx.y;
    int nchunk = gridDim.y;
    int s2 = blockIdx.x * 512 + threadIdx.x * 2;
    size_t base = ((size_t)bl * C + (size_t)chunk * CCH) * NS + s2;
    float ax0 = 0.f, ax1 = 0.f, ay0 = 0.f, ay1 = 0.f;
    #pragma unroll 8
    for (int c = 0; c < CCH; ++c) {
        unsigned xv = *(const unsigned*)&Xt[base + (size_t)c * NS];
        unsigned yv = *(const unsigned*)&Yt[base + (size_t)c * NS];
        float x0 = bf2f((u16)xv), x1 = bf2f((u16)(xv >> 16));
        float y0 = bf2f((u16)yv), y1 = bf2f((u16)(yv >> 16));
        ax0 = fmaf(x0, x0, ax0); ax1 = fmaf(x1, x1, ax1);
        ay0 = fmaf(y0, y0, ay0); ay1 = fmaf(y1, y1, ay1);
    }
    size_t o = ((size_t)bl * nchunk + chunk) * NS + s2;
    *(float2*)&xp[o] = make_float2(ax0, ax1);
    *(float2*)&yp[o] = make_float2(ay0, ay1);
}

// Reduce partials -> norms; also init the min buffers (saves 2 memsets/layer).
__global__ void colnorm_reduce(const float* __restrict__ xp, const float* __restrict__ yp,
                               float* __restrict__ xn, float* __restrict__ yn,
                               unsigned* __restrict__ m1u, unsigned* __restrict__ m2u,
                               int nchunk)
{
    int bl = blockIdx.y;
    int s = blockIdx.x * 256 + threadIdx.x;
    float ax = 0.f, ay = 0.f;
    for (int k = 0; k < nchunk; ++k) {
        size_t o = ((size_t)bl * nchunk + k) * NS + s;
        ax += xp[o];
        ay += yp[o];
    }
    xn[bl * NS + s] = sqrtf(ax);
    yn[bl * NS + s] = sqrtf(ay);
    m1u[bl * NS + s] = 0xFFFFFFFFu;
    m2u[bl * NS + s] = 0xFFFFFFFFu;
}

// 64x64 tile transpose: Zn[s][c] = Zt[c][s] / zn[s]; z encodes (bl, X-or-Y).
__global__ void transpose_norm(const u16* __restrict__ Xt, const u16* __restrict__ Yt,
                               const float* __restrict__ xn, const float* __restrict__ yn,
                               u16* __restrict__ Xn, u16* __restrict__ Yn, int C)
{
    int z = blockIdx.z;
    int bl = z >> 1, which = z & 1;
    const u16* Zt = which ? Yt : Xt;
    const float* zn = which ? yn : xn;
    u16* Zn = which ? Yn : Xn;
    int c0 = blockIdx.x * 64, s0 = blockIdx.y * 64;
    __shared__ __align__(16) u16 T[64][72];
    int tid = threadIdx.x;
    #pragma unroll
    for (int rep = 0; rep < 2; ++rep) {
        int q = tid + rep * 256;
        int rr = q >> 3, seg = q & 7;
        *(float4*)&T[rr][seg * 8] =
            *(const float4*)&Zt[((size_t)bl * C + c0 + rr) * NS + s0 + seg * 8];
    }
    __syncthreads();
    #pragma unroll
    for (int rep = 0; rep < 2; ++rep) {
        int q = tid + rep * 256;
        int sr = q >> 3, cs = q & 7;
        float inv = 1.0f / zn[bl * NS + s0 + sr];
        __align__(16) u16 tmp[8];
        #pragma unroll
        for (int e = 0; e < 8; ++e) tmp[e] = f2bf(bf2f(T[cs * 8 + e][sr]) * inv);
        *(float4*)&Zn[((size_t)bl * NS + s0 + sr) * C + c0 + cs * 8] = *(float4*)tmp;
    }
}

// Channel sums (warp per channel, coalesced over s, deterministic shuffle tree).
__global__ void chansum(const u16* __restrict__ Xt, const u16* __restrict__ Yt,
                        float* __restrict__ sx, float* __restrict__ sy, int C)
{
    int bl = blockIdx.y;
    int c = blockIdx.x * 4 + (threadIdx.x >> 6);
    int lane = threadIdx.x & 63;
    const u16* xb = Xt + ((size_t)bl * C + c) * NS;
    const u16* yb = Yt + ((size_t)bl * C + c) * NS;
    float ax = 0.f, ay = 0.f;
    for (int s = lane; s < NS; s += 64) { ax += bf2f(xb[s]); ay += bf2f(yb[s]); }
    for (int o = 32; o > 0; o >>= 1) { ax += __shfl_down(ax, o); ay += __shfl_down(ay, o); }
    if (lane == 0) { sx[bl * C + c] = ax; sy[bl * C + c] = ay; }
}

// 128x128 MFMA tile of cos-dist = 1 - Xn.Yn^T; fused row/col min epilogue.
__global__ __launch_bounds__(256) void cross_mfma(
    const u16* __restrict__ Xn, const u16* __restrict__ Yn,
    unsigned* __restrict__ m1u, unsigned* __restrict__ m2u, int C)
{
    int bl = blockIdx.z;
    int i0 = blockIdx.x * 128, j0 = blockIdx.y * 128;
    __shared__ __align__(16) u16 As[128][40], Bs[128][40];
    int tid = threadIdx.x;
    int w = tid >> 6, lane = tid & 63;
    int wr = w >> 1, wc = w & 1;
    int q = lane >> 4, r = lane & 15;
    const u16* Xb = Xn + ((size_t)bl * NS + i0) * C;
    const u16* Yb = Yn + ((size_t)bl * NS + j0) * C;
    f32x4 acc[4][4];
    #pragma unroll
    for (int m = 0; m < 4; ++m)
        #pragma unroll
        for (int nn = 0; nn < 4; ++nn) acc[m][nn] = (f32x4){0.f, 0.f, 0.f, 0.f};

    for (int kk = 0; kk < C; kk += 32) {
        __syncthreads();
        #pragma unroll
        for (int rep = 0; rep < 2; ++rep) {
            int qid = tid + rep * 256;
            int row = qid >> 2, seg = qid & 3;
            size_t off = (size_t)row * C + kk + seg * 8;
            *(float4*)&As[row][seg * 8] = *(const float4*)&Xb[off];
            *(float4*)&Bs[row][seg * 8] = *(const float4*)&Yb[off];
        }
        __syncthreads();
        bf16x8 a[4], b[4];
        #pragma unroll
        for (int m = 0; m < 4; ++m)
            a[m] = *(const bf16x8*)&As[wr * 64 + m * 16 + r][q * 8];
        #pragma unroll
        for (int nn = 0; nn < 4; ++nn)
            b[nn] = *(const bf16x8*)&Bs[wc * 64 + nn * 16 + r][q * 8];
        #pragma unroll
        for (int m = 0; m < 4; ++m)
            #pragma unroll
            for (int nn = 0; nn < 4; ++nn)
                acc[m][nn] = __builtin_amdgcn_mfma_f32_16x16x32_bf16(a[m], b[nn], acc[m][nn], 0, 0, 0);
    }

    float rm[4][4];
    float cm[4];
    #pragma unroll
    for (int m = 0; m < 4; ++m)
        #pragma unroll
        for (int reg = 0; reg < 4; ++reg) rm[m][reg] = 1e30f;
    #pragma unroll
    for (int nn = 0; nn < 4; ++nn) cm[nn] = 1e30f;
    #pragma unroll
    for (int m = 0; m < 4; ++m)
        #pragma unroll
        for (int nn = 0; nn < 4; ++nn)
            #pragma unroll
            for (int reg = 0; reg < 4; ++reg) {
                float d = 1.f - acc[m][nn][reg];
                rm[m][reg] = fminf(rm[m][reg], d);
                cm[nn] = fminf(cm[nn], d);
            }
    #pragma unroll
    for (int m = 0; m < 4; ++m)
        #pragma unroll
        for (int reg = 0; reg < 4; ++reg) {
            float v = rm[m][reg];
            v = fminf(v, __shfl_xor(v, 1));
            v = fminf(v, __shfl_xor(v, 2));
            v = fminf(v, __shfl_xor(v, 4));
            v = fminf(v, __shfl_xor(v, 8));
            rm[m][reg] = v;
        }
    if (r == 0) {
        #pragma unroll
        for (int m = 0; m < 4; ++m)
            #pragma unroll
            for (int reg = 0; reg < 4; ++reg) {
                int i = i0 + wr * 64 + m * 16 + q * 4 + reg;
                atomicMin(&m2u[bl * NS + i], fenc(rm[m][reg]));
            }
    }
    #pragma unroll
    for (int nn = 0; nn < 4; ++nn) {
        float v = cm[nn];
        v = fminf(v, __shfl_xor(v, 16));
        v = fminf(v, __shfl_xor(v, 32));
        cm[nn] = v;
    }
    if (q == 0) {
        #pragma unroll
        for (int nn = 0; nn < 4; ++nn) {
            int j = j0 + wc * 64 + nn * 16 + r;
            atomicMin(&m1u[bl * NS + j], fenc(cm[nn]));
        }
    }
}

// Dual 128x128 MFMA tile of Sxx and Syy; upper-triangle tiles, off-diag weighted 2x.
__global__ __launch_bounds__(256) void cov_mfma(
    const u16* __restrict__ Xt, const u16* __restrict__ Yt,
    const float* __restrict__ sx, const float* __restrict__ sy,
    float* __restrict__ covpart, int C, int ntri)
{
    int bl = blockIdx.y;
    int u = blockIdx.x;
    int ty = 0;
    while ((ty + 1) * (ty + 2) / 2 <= u) ++ty;
    int tx = u - ty * (ty + 1) / 2;
    int c0 = ty * 128, d0 = tx * 128;
    float wgt = (tx == ty) ? 1.f : 2.f;

    __shared__ __align__(16) u16 As[128][40], Bs[128][40], Cs2[128][40], Ds[128][40];
    int tid = threadIdx.x;
    int w = tid >> 6, lane = tid & 63;
    int wr = w >> 1, wc = w & 1;
    int q = lane >> 4, r = lane & 15;
    const u16* Xc = Xt + ((size_t)bl * C + c0) * NS;
    const u16* Xd = Xt + ((size_t)bl * C + d0) * NS;
    const u16* Yc = Yt + ((size_t)bl * C + c0) * NS;
    const u16* Yd = Yt + ((size_t)bl * C + d0) * NS;

    f32x4 accX[4][4], accY[4][4];
    #pragma unroll
    for (int m = 0; m < 4; ++m)
        #pragma unroll
        for (int nn = 0; nn < 4; ++nn) {
            accX[m][nn] = (f32x4){0.f, 0.f, 0.f, 0.f};
            accY[m][nn] = (f32x4){0.f, 0.f, 0.f, 0.f};
        }

    for (int ss = 0; ss < NS; ss += 32) {
        __syncthreads();
        #pragma unroll
        for (int rep = 0; rep < 2; ++rep) {
            int qid = tid + rep * 256;
            int row = qid >> 2, seg = qid & 3;
            size_t off = (size_t)row * NS + ss + seg * 8;
            *(float4*)&As[row][seg * 8]  = *(const float4*)&Xc[off];
            *(float4*)&Bs[row][seg * 8]  = *(const float4*)&Xd[off];
            *(float4*)&Cs2[row][seg * 8] = *(const float4*)&Yc[off];
            *(float4*)&Ds[row][seg * 8]  = *(const float4*)&Yd[off];
        }
        __syncthreads();
        {
            bf16x8 a[4], b[4];
            #pragma unroll
            for (int m = 0; m < 4; ++m) a[m] = *(const bf16x8*)&As[wr * 64 + m * 16 + r][q * 8];
            #pragma unroll
            for (int nn = 0; nn < 4; ++nn) b[nn] = *(const bf16x8*)&Bs[wc * 64 + nn * 16 + r][q * 8];
            #pragma unroll
            for (int m = 0; m < 4; ++m)
                #pragma unroll
                for (int nn = 0; nn < 4; ++nn)
                    accX[m][nn] = __builtin_amdgcn_mfma_f32_16x16x32_bf16(a[m], b[nn], accX[m][nn], 0, 0, 0);
        }
        {
            bf16x8 a[4], b[4];
            #pragma unroll
            for (int m = 0; m < 4; ++m) a[m] = *(const bf16x8*)&Cs2[wr * 64 + m * 16 + r][q * 8];
            #pragma unroll
            for (int nn = 0; nn < 4; ++nn) b[nn] = *(const bf16x8*)&Ds[wc * 64 + nn * 16 + r][q * 8];
            #pragma unroll
            for (int m = 0; m < 4; ++m)
                #pragma unroll
                for (int nn = 0; nn < 4; ++nn)
                    accY[m][nn] = __builtin_amdgcn_mfma_f32_16x16x32_bf16(a[m], b[nn], accY[m][nn], 0, 0, 0);
        }
    }

    float scxv[4][4], scyv[4][4], sdxv[4], sdyv[4];
    #pragma unroll
    for (int m = 0; m < 4; ++m)
        #pragma unroll
        for (int reg = 0; reg < 4; ++reg) {
            int c = c0 + wr * 64 + m * 16 + q * 4 + reg;
            scxv[m][reg] = sx[bl * C + c];
            scyv[m][reg] = sy[bl * C + c];
        }
    #pragma unroll
    for (int nn = 0; nn < 4; ++nn) {
        int d = d0 + wc * 64 + nn * 16 + r;
        sdxv[nn] = sx[bl * C + d];
        sdyv[nn] = sy[bl * C + d];
    }
    const float invNS = 1.f / NS, invNSm1 = 1.f / (NS - 1);
    float tsum = 0.f;
    #pragma unroll
    for (int m = 0; m < 4; ++m)
        #pragma unroll
        for (int nn = 0; nn < 4; ++nn)
            #pragma unroll
            for (int reg = 0; reg < 4; ++reg) {
                float cx = (accX[m][nn][reg] - scxv[m][reg] * sdxv[nn] * invNS) * invNSm1;
                float cy = (accY[m][nn][reg] - scyv[m][reg] * sdyv[nn] * invNS) * invNSm1;
                tsum += fabsf(cx - cy);
            }
    tsum *= wgt;
    __shared__ float redc[4];
    for (int o = 32; o > 0; o >>= 1) tsum += __shfl_down(tsum, o);
    if (lane == 0) redc[w] = tsum;
    __syncthreads();
    if (tid == 0)
        covpart[(size_t)bl * ntri + u] = redc[0] + redc[1] + redc[2] + redc[3];
}

__global__ void finalize_kernel(const unsigned* __restrict__ m1u, const unsigned* __restrict__ m2u,
                                const float* __restrict__ sx, const float* __restrict__ sy,
                                const float* __restrict__ covpart, int ntri,
                                float* __restrict__ loss_acc, int C, int b0)
{
    int bl = blockIdx.x;
    int tid = threadIdx.x;
    float s1 = 0.f, s2 = 0.f, smu = 0.f, scov = 0.f;
    for (int s = tid; s < NS; s += 256) {
        s1 += fdec(m1u[bl * NS + s]);
        s2 += fdec(m2u[bl * NS + s]);
    }
    for (int c = tid; c < C; c += 256) smu += fabsf(sx[bl * C + c] - sy[bl * C + c]);
    for (int i = tid; i < ntri; i += 256) scov += covpart[(size_t)bl * ntri + i];
    __shared__ float red[4][4];
    for (int o = 32; o > 0; o >>= 1) {
        s1 += __shfl_down(s1, o);
        s2 += __shfl_down(s2, o);
        smu += __shfl_down(smu, o);
        scov += __shfl_down(scov, o);
    }
    int wid = tid >> 6, lane = tid & 63;
    if (lane == 0) { red[0][wid] = s1; red[1][wid] = s2; red[2][wid] = smu; red[3][wid] = scov; }
    __syncthreads();
    if (tid == 0) {
        s1 = red[0][0] + red[0][1] + red[0][2] + red[0][3];
        s2 = red[1][0] + red[1][1] + red[1][2] + red[1][3];
        smu = red[2][0] + red[2][1] + red[2][2] + red[2][3];
        scov = red[3][0] + red[3][1] + red[3][2] + red[3][3];
        float m1m = s1 * (1.f / NS), m2m = s2 * (1.f / NS);
        float mu_diff = smu * (1.f / NS) * (1.f / (float)C);
        float cov_diff = scov / ((float)C * (float)C);
        loss_acc[b0 + bl] += fmaxf(m1m, m2m) + mu_diff + cov_diff;
    }
}

__global__ void out_kernel(const float* __restrict__ loss_acc, float* __restrict__ out)
{
    int t = threadIdx.x;
    if (t < NT) {
        float s = 0.f;
        for (int k = 0; k < BSZ; ++k) s += loss_acc[k * NT + t];
        out[t] = s * (1.f / BSZ);
    }
}

static inline size_t alignup(size_t v) { return (v + 255) & ~(size_t)255; }

extern "C" void kernel_launch(void* const* d_in, const int* in_sizes, int n_in,
                              void* d_out, int out_size, void* d_ws, size_t ws_size,
                              hipStream_t stream)
{
    const float* tp[3] = {(const float*)d_in[0], (const float*)d_in[4], (const float*)d_in[8]};
    const float* gp[3] = {(const float*)d_in[1], (const float*)d_in[5], (const float*)d_in[9]};
    const int* ixp[3]  = {(const int*)d_in[2], (const int*)d_in[6], (const int*)d_in[10]};
    const int* iyp[3]  = {(const int*)d_in[3], (const int*)d_in[7], (const int*)d_in[11]};
    const int Cs[3] = {128, 256, 512};
    const int Sp[3] = {128, 64, 32};

    float* out = (float*)d_out;
    char* ws = (char*)d_ws;
    float* loss_acc = (float*)ws;
    size_t base = 256;
    hipMemsetAsync(loss_acc, 0, BB * sizeof(float), stream);

    for (int l = 0; l < 3; ++l) {
        int C = Cs[l];
        int n = Sp[l] * Sp[l];
        int tc = C / 128;
        int ntri = tc * (tc + 1) / 2;
        int nchunk = C / CCH;
        size_t szZ = alignup((size_t)NS * C * 2);
        size_t szP = alignup((size_t)nchunk * NS * 4);
        size_t per_b = 4 * szZ                      // Xt, Yt, Xn, Yn
                     + 2 * szP                      // xp, yp
                     + 2 * alignup(NS * 4)          // xn, yn
                     + 2 * alignup(C * 4)           // sx, sy
                     + 2 * alignup(NS * 4)          // m1u, m2u
                     + alignup(ntri * 4);           // covpart
        size_t avail = (ws_size > base) ? ws_size - base : 0;
        int G = (int)(avail / per_b);
        if (G > BB) G = BB;
        if (G < 1) G = 1;

        for (int b0 = 0; b0 < BB; b0 += G) {
            int nb = (BB - b0 < G) ? (BB - b0) : G;
            char* p = ws + base;
            u16* Xt = (u16*)p;  p += nb * szZ;
            u16* Yt = (u16*)p;  p += nb * szZ;
            u16* Xn = (u16*)p;  p += nb * szZ;
            u16* Yn = (u16*)p;  p += nb * szZ;
            float* xp = (float*)p; p += nb * szP;
            float* yp = (float*)p; p += nb * szP;
            float* xn = (float*)p; p += nb * alignup(NS * 4);
            float* yn = (float*)p; p += nb * alignup(NS * 4);
            float* sx = (float*)p; p += nb * alignup(C * 4);
            float* sy = (float*)p; p += nb * alignup(C * 4);
            unsigned* m1u = (unsigned*)p; p += nb * alignup(NS * 4);
            unsigned* m2u = (unsigned*)p; p += nb * alignup(NS * 4);
            float* covpart = (float*)p;   p += nb * alignup(ntri * 4);

            gather_t<<<dim3(C, nb), 256, 0, stream>>>(gp[l], tp[l], ixp[l], iyp[l],
                                                      Xt, Yt, C, n, b0);
            colnorm_part<<<dim3(NS / 512, nchunk, nb), 256, 0, stream>>>(Xt, Yt, xp, yp, C);
            colnorm_reduce<<<dim3(NS / 256, nb), 256, 0, stream>>>(xp, yp, xn, yn,
                                                                   m1u, m2u, nchunk);
            transpose_norm<<<dim3(C / 64, NS / 64, nb * 2), 256, 0, stream>>>(
                Xt, Yt, xn, yn, Xn, Yn, C);
            chansum<<<dim3(C / 4, nb), 256, 0, stream>>>(Xt, Yt, sx, sy, C);
            cross_mfma<<<dim3(NS / 128, NS / 128, nb), 256, 0, stream>>>(Xn, Yn, m1u, m2u, C);
            cov_mfma<<<dim3(ntri, nb), 256, 0, stream>>>(Xt, Yt, sx, sy, covpart, C, ntri);
            finalize_kernel<<<nb, 256, 0, stream>>>(m1u, m2u, sx, sy, covpart, ntri,
                                                    loss_acc, C, b0);
        }
    }
    out_kernel<<<1, 64, 0, stream>>>(loss_acc, out);
}

// Round 4
// 254.108 us; speedup vs baseline: 5.4875x; 1.6766x over previous
//
#include <hip/hip_runtime.h>
#include <math.h>

#define NT 4
#define BSZ 4
#define BB 16
#define NS 1024
#define CCH 32
#define MAXL 3

typedef unsigned short u16;
typedef __attribute__((ext_vector_type(8))) short bf16x8;
typedef __attribute__((ext_vector_type(4))) float f32x4;

struct LayerP {
    const float *g, *t;
    const int *ix, *iy;
    u16 *Xt, *Yt, *Xn, *Yn;
    float *xp, *yp, *xnv, *ynv, *sx, *sy;
    unsigned *m1u, *m2u;
    float *cov;
    int C, n, nchunk, ntri, lid;
};
struct Tab {
    LayerP L[MAXL];
    int nl, nb, b0;
    float* losspart;   // [BB][3]
};

__device__ __forceinline__ unsigned fenc(float f) {
    unsigned u = __float_as_uint(f);
    return (u & 0x80000000u) ? ~u : (u | 0x80000000u);
}
__device__ __forceinline__ float fdec(unsigned u) {
    unsigned v = (u & 0x80000000u) ? (u & 0x7FFFFFFFu) : ~u;
    return __uint_as_float(v);
}
__device__ __forceinline__ u16 f2bf(float f) {  // RNE
    unsigned u = __float_as_uint(f);
    unsigned r = u + 0x7FFFu + ((u >> 16) & 1u);
    return (u16)(r >> 16);
}
__device__ __forceinline__ float bf2f(u16 h) {
    return __uint_as_float((unsigned)h << 16);
}

// Gather channel-major bf16 + fused per-channel sums (was chansum kernel).
__global__ void gather_t(Tab tab)
{
    int x = blockIdx.x, l = 0;
    while (l < MAXL - 1 && x >= tab.L[l].C) { x -= tab.L[l].C; ++l; }
    const LayerP P = tab.L[l];
    int c = x, bl = blockIdx.y, bg = tab.b0 + bl;
    int tid = threadIdx.x;
    const float* __restrict__ grow = P.g + ((size_t)bg * P.C + c) * P.n;
    const float* __restrict__ trow = P.t + ((size_t)(bg % NT) * P.C + c) * P.n;
    const int* __restrict__ ixr = P.ix + bg * NS;
    const int* __restrict__ iyr = P.iy + bg * NS;
    u16* __restrict__ xo = P.Xt + ((size_t)bl * P.C + c) * NS;
    u16* __restrict__ yo = P.Yt + ((size_t)bl * P.C + c) * NS;
    float ax = 0.f, ay = 0.f;
    #pragma unroll
    for (int rep = 0; rep < NS / 256; ++rep) {
        int s = tid + rep * 256;
        u16 xb = f2bf(grow[ixr[s]]);
        u16 yb = f2bf(trow[iyr[s]]);
        xo[s] = xb;
        yo[s] = yb;
        ax += bf2f(xb);
        ay += bf2f(yb);
    }
    __shared__ float red[2][4];
    for (int o = 32; o > 0; o >>= 1) { ax += __shfl_down(ax, o); ay += __shfl_down(ay, o); }
    int wid = tid >> 6, lane = tid & 63;
    if (lane == 0) { red[0][wid] = ax; red[1][wid] = ay; }
    __syncthreads();
    if (tid == 0) {
        P.sx[bl * P.C + c] = red[0][0] + red[0][1] + red[0][2] + red[0][3];
        P.sy[bl * P.C + c] = red[1][0] + red[1][1] + red[1][2] + red[1][3];
    }
}

// Partial sums of squares over CCH-channel chunks (2 samples/thread, uint loads).
__global__ void colnorm_part(Tab tab)
{
    int y = blockIdx.y, l = 0;
    while (l < MAXL - 1 && y >= tab.L[l].nchunk) { y -= tab.L[l].nchunk; ++l; }
    const LayerP P = tab.L[l];
    int chunk = y, bl = blockIdx.z;
    int s2 = blockIdx.x * 512 + threadIdx.x * 2;
    size_t base = ((size_t)bl * P.C + (size_t)chunk * CCH) * NS + s2;
    const u16* __restrict__ Xt = P.Xt;
    const u16* __restrict__ Yt = P.Yt;
    float ax0 = 0.f, ax1 = 0.f, ay0 = 0.f, ay1 = 0.f;
    #pragma unroll 8
    for (int c = 0; c < CCH; ++c) {
        unsigned xv = *(const unsigned*)&Xt[base + (size_t)c * NS];
        unsigned yv = *(const unsigned*)&Yt[base + (size_t)c * NS];
        float x0 = bf2f((u16)xv), x1 = bf2f((u16)(xv >> 16));
        float y0 = bf2f((u16)yv), y1 = bf2f((u16)(yv >> 16));
        ax0 = fmaf(x0, x0, ax0); ax1 = fmaf(x1, x1, ax1);
        ay0 = fmaf(y0, y0, ay0); ay1 = fmaf(y1, y1, ay1);
    }
    size_t o = ((size_t)bl * P.nchunk + chunk) * NS + s2;
    *(float2*)&P.xp[o] = make_float2(ax0, ax1);
    *(float2*)&P.yp[o] = make_float2(ay0, ay1);
}

// Reduce partials -> norms; also init min buffers.
__global__ void colnorm_reduce(Tab tab)
{
    const LayerP P = tab.L[blockIdx.y];
    int bl = blockIdx.z;
    int s = blockIdx.x * 256 + threadIdx.x;
    float ax = 0.f, ay = 0.f;
    for (int k = 0; k < P.nchunk; ++k) {
        size_t o = ((size_t)bl * P.nchunk + k) * NS + s;
        ax += P.xp[o];
        ay += P.yp[o];
    }
    P.xnv[bl * NS + s] = sqrtf(ax);
    P.ynv[bl * NS + s] = sqrtf(ay);
    P.m1u[bl * NS + s] = 0xFFFFFFFFu;
    P.m2u[bl * NS + s] = 0xFFFFFFFFu;
}

// 64x64 tile transpose: Zn[s][c] = Zt[c][s] / zn[s]; z encodes (bl, X-or-Y).
__global__ void transpose_norm(Tab tab)
{
    int x = blockIdx.x, l = 0;
    while (l < MAXL - 1 && x >= tab.L[l].C / 64) { x -= tab.L[l].C / 64; ++l; }
    const LayerP P = tab.L[l];
    int z = blockIdx.z;
    int bl = z >> 1, which = z & 1;
    const u16* __restrict__ Zt = which ? P.Yt : P.Xt;
    const float* __restrict__ zn = which ? P.ynv : P.xnv;
    u16* __restrict__ Zn = which ? P.Yn : P.Xn;
    int C = P.C;
    int c0 = x * 64, s0 = blockIdx.y * 64;
    __shared__ __align__(16) u16 T[64][72];
    int tid = threadIdx.x;
    #pragma unroll
    for (int rep = 0; rep < 2; ++rep) {
        int q = tid + rep * 256;
        int rr = q >> 3, seg = q & 7;
        *(float4*)&T[rr][seg * 8] =
            *(const float4*)&Zt[((size_t)bl * C + c0 + rr) * NS + s0 + seg * 8];
    }
    __syncthreads();
    #pragma unroll
    for (int rep = 0; rep < 2; ++rep) {
        int q = tid + rep * 256;
        int sr = q >> 3, cs = q & 7;
        float inv = 1.0f / zn[bl * NS + s0 + sr];
        __align__(16) u16 tmp[8];
        #pragma unroll
        for (int e = 0; e < 8; ++e) tmp[e] = f2bf(bf2f(T[cs * 8 + e][sr]) * inv);
        *(float4*)&Zn[((size_t)bl * NS + s0 + sr) * C + c0 + cs * 8] = *(float4*)tmp;
    }
}

// 128x128 MFMA tile of cos-dist = 1 - Xn.Yn^T; fused row/col min epilogue.
__global__ __launch_bounds__(256) void cross_mfma(Tab tab)
{
    int z = blockIdx.z;
    int l = z / tab.nb, bl = z - l * tab.nb;
    const LayerP P = tab.L[l];
    int C = P.C;
    int i0 = blockIdx.x * 128, j0 = blockIdx.y * 128;
    __shared__ __align__(16) u16 As[128][40], Bs[128][40];
    int tid = threadIdx.x;
    int w = tid >> 6, lane = tid & 63;
    int wr = w >> 1, wc = w & 1;
    int q = lane >> 4, r = lane & 15;
    const u16* __restrict__ Xb = P.Xn + ((size_t)bl * NS + i0) * C;
    const u16* __restrict__ Yb = P.Yn + ((size_t)bl * NS + j0) * C;
    f32x4 acc[4][4];
    #pragma unroll
    for (int m = 0; m < 4; ++m)
        #pragma unroll
        for (int nn = 0; nn < 4; ++nn) acc[m][nn] = (f32x4){0.f, 0.f, 0.f, 0.f};

    for (int kk = 0; kk < C; kk += 32) {
        __syncthreads();
        #pragma unroll
        for (int rep = 0; rep < 2; ++rep) {
            int qid = tid + rep * 256;
            int row = qid >> 2, seg = qid & 3;
            size_t off = (size_t)row * C + kk + seg * 8;
            *(float4*)&As[row][seg * 8] = *(const float4*)&Xb[off];
            *(float4*)&Bs[row][seg * 8] = *(const float4*)&Yb[off];
        }
        __syncthreads();
        bf16x8 a[4], b[4];
        #pragma unroll
        for (int m = 0; m < 4; ++m)
            a[m] = *(const bf16x8*)&As[wr * 64 + m * 16 + r][q * 8];
        #pragma unroll
        for (int nn = 0; nn < 4; ++nn)
            b[nn] = *(const bf16x8*)&Bs[wc * 64 + nn * 16 + r][q * 8];
        #pragma unroll
        for (int m = 0; m < 4; ++m)
            #pragma unroll
            for (int nn = 0; nn < 4; ++nn)
                acc[m][nn] = __builtin_amdgcn_mfma_f32_16x16x32_bf16(a[m], b[nn], acc[m][nn], 0, 0, 0);
    }

    float rm[4][4], cm[4];
    #pragma unroll
    for (int m = 0; m < 4; ++m)
        #pragma unroll
        for (int reg = 0; reg < 4; ++reg) rm[m][reg] = 1e30f;
    #pragma unroll
    for (int nn = 0; nn < 4; ++nn) cm[nn] = 1e30f;
    #pragma unroll
    for (int m = 0; m < 4; ++m)
        #pragma unroll
        for (int nn = 0; nn < 4; ++nn)
            #pragma unroll
            for (int reg = 0; reg < 4; ++reg) {
                float d = 1.f - acc[m][nn][reg];
                rm[m][reg] = fminf(rm[m][reg], d);
                cm[nn] = fminf(cm[nn], d);
            }
    #pragma unroll
    for (int m = 0; m < 4; ++m)
        #pragma unroll
        for (int reg = 0; reg < 4; ++reg) {
            float v = rm[m][reg];
            v = fminf(v, __shfl_xor(v, 1));
            v = fminf(v, __shfl_xor(v, 2));
            v = fminf(v, __shfl_xor(v, 4));
            v = fminf(v, __shfl_xor(v, 8));
            rm[m][reg] = v;
        }
    if (r == 0) {
        #pragma unroll
        for (int m = 0; m < 4; ++m)
            #pragma unroll
            for (int reg = 0; reg < 4; ++reg) {
                int i = i0 + wr * 64 + m * 16 + q * 4 + reg;
                atomicMin(&P.m2u[bl * NS + i], fenc(rm[m][reg]));
            }
    }
    #pragma unroll
    for (int nn = 0; nn < 4; ++nn) {
        float v = cm[nn];
        v = fminf(v, __shfl_xor(v, 16));
        v = fminf(v, __shfl_xor(v, 32));
        cm[nn] = v;
    }
    if (q == 0) {
        #pragma unroll
        for (int nn = 0; nn < 4; ++nn) {
            int j = j0 + wc * 64 + nn * 16 + r;
            atomicMin(&P.m1u[bl * NS + j], fenc(cm[nn]));
        }
    }
}

// Dual 128x128 MFMA tile of Sxx/Syy; upper-triangle tiles, off-diag weighted 2x.
__global__ __launch_bounds__(256) void cov_mfma(Tab tab)
{
    int x = blockIdx.x, l = 0;
    while (l < MAXL - 1 && x >= tab.L[l].ntri) { x -= tab.L[l].ntri; ++l; }
    const LayerP P = tab.L[l];
    int u = x;
    int bl = blockIdx.y;
    int C = P.C;
    int ty = 0;
    while ((ty + 1) * (ty + 2) / 2 <= u) ++ty;
    int tx = u - ty * (ty + 1) / 2;
    int c0 = ty * 128, d0 = tx * 128;
    float wgt = (tx == ty) ? 1.f : 2.f;

    __shared__ __align__(16) u16 As[128][40], Bs[128][40], Cs2[128][40], Ds[128][40];
    int tid = threadIdx.x;
    int w = tid >> 6, lane = tid & 63;
    int wr = w >> 1, wc = w & 1;
    int q = lane >> 4, r = lane & 15;
    const u16* __restrict__ Xc = P.Xt + ((size_t)bl * C + c0) * NS;
    const u16* __restrict__ Xd = P.Xt + ((size_t)bl * C + d0) * NS;
    const u16* __restrict__ Yc = P.Yt + ((size_t)bl * C + c0) * NS;
    const u16* __restrict__ Yd = P.Yt + ((size_t)bl * C + d0) * NS;

    f32x4 accX[4][4], accY[4][4];
    #pragma unroll
    for (int m = 0; m < 4; ++m)
        #pragma unroll
        for (int nn = 0; nn < 4; ++nn) {
            accX[m][nn] = (f32x4){0.f, 0.f, 0.f, 0.f};
            accY[m][nn] = (f32x4){0.f, 0.f, 0.f, 0.f};
        }

    for (int ss = 0; ss < NS; ss += 32) {
        __syncthreads();
        #pragma unroll
        for (int rep = 0; rep < 2; ++rep) {
            int qid = tid + rep * 256;
            int row = qid >> 2, seg = qid & 3;
            size_t off = (size_t)row * NS + ss + seg * 8;
            *(float4*)&As[row][seg * 8]  = *(const float4*)&Xc[off];
            *(float4*)&Bs[row][seg * 8]  = *(const float4*)&Xd[off];
            *(float4*)&Cs2[row][seg * 8] = *(const float4*)&Yc[off];
            *(float4*)&Ds[row][seg * 8]  = *(const float4*)&Yd[off];
        }
        __syncthreads();
        {
            bf16x8 a[4], b[4];
            #pragma unroll
            for (int m = 0; m < 4; ++m) a[m] = *(const bf16x8*)&As[wr * 64 + m * 16 + r][q * 8];
            #pragma unroll
            for (int nn = 0; nn < 4; ++nn) b[nn] = *(const bf16x8*)&Bs[wc * 64 + nn * 16 + r][q * 8];
            #pragma unroll
            for (int m = 0; m < 4; ++m)
                #pragma unroll
                for (int nn = 0; nn < 4; ++nn)
                    accX[m][nn] = __builtin_amdgcn_mfma_f32_16x16x32_bf16(a[m], b[nn], accX[m][nn], 0, 0, 0);
        }
        {
            bf16x8 a[4], b[4];
            #pragma unroll
            for (int m = 0; m < 4; ++m) a[m] = *(const bf16x8*)&Cs2[wr * 64 + m * 16 + r][q * 8];
            #pragma unroll
            for (int nn = 0; nn < 4; ++nn) b[nn] = *(const bf16x8*)&Ds[wc * 64 + nn * 16 + r][q * 8];
            #pragma unroll
            for (int m = 0; m < 4; ++m)
                #pragma unroll
                for (int nn = 0; nn < 4; ++nn)
                    accY[m][nn] = __builtin_amdgcn_mfma_f32_16x16x32_bf16(a[m], b[nn], accY[m][nn], 0, 0, 0);
        }
    }

    float scxv[4][4], scyv[4][4], sdxv[4], sdyv[4];
    #pragma unroll
    for (int m = 0; m < 4; ++m)
        #pragma unroll
        for (int reg = 0; reg < 4; ++reg) {
            int c = c0 + wr * 64 + m * 16 + q * 4 + reg;
            scxv[m][reg] = P.sx[bl * C + c];
            scyv[m][reg] = P.sy[bl * C + c];
        }
    #pragma unroll
    for (int nn = 0; nn < 4; ++nn) {
        int d = d0 + wc * 64 + nn * 16 + r;
        sdxv[nn] = P.sx[bl * C + d];
        sdyv[nn] = P.sy[bl * C + d];
    }
    const float invNS = 1.f / NS, invNSm1 = 1.f / (NS - 1);
    float tsum = 0.f;
    #pragma unroll
    for (int m = 0; m < 4; ++m)
        #pragma unroll
        for (int nn = 0; nn < 4; ++nn)
            #pragma unroll
            for (int reg = 0; reg < 4; ++reg) {
                float cx = (accX[m][nn][reg] - scxv[m][reg] * sdxv[nn] * invNS) * invNSm1;
                float cy = (accY[m][nn][reg] - scyv[m][reg] * sdyv[nn] * invNS) * invNSm1;
                tsum += fabsf(cx - cy);
            }
    tsum *= wgt;
    __shared__ float redc[4];
    for (int o = 32; o > 0; o >>= 1) tsum += __shfl_down(tsum, o);
    if (lane == 0) redc[w] = tsum;
    __syncthreads();
    if (tid == 0)
        P.cov[(size_t)bl * P.ntri + u] = redc[0] + redc[1] + redc[2] + redc[3];
}

__global__ void finalize_kernel(Tab tab)
{
    const LayerP P = tab.L[blockIdx.x];
    int bl = blockIdx.y;
    int tid = threadIdx.x;
    int C = P.C;
    float s1 = 0.f, s2 = 0.f, smu = 0.f, scov = 0.f;
    for (int s = tid; s < NS; s += 256) {
        s1 += fdec(P.m1u[bl * NS + s]);
        s2 += fdec(P.m2u[bl * NS + s]);
    }
    for (int c = tid; c < C; c += 256) smu += fabsf(P.sx[bl * C + c] - P.sy[bl * C + c]);
    for (int i = tid; i < P.ntri; i += 256) scov += P.cov[(size_t)bl * P.ntri + i];
    __shared__ float red[4][4];
    for (int o = 32; o > 0; o >>= 1) {
        s1 += __shfl_down(s1, o);
        s2 += __shfl_down(s2, o);
        smu += __shfl_down(smu, o);
        scov += __shfl_down(scov, o);
    }
    int wid = tid >> 6, lane = tid & 63;
    if (lane == 0) { red[0][wid] = s1; red[1][wid] = s2; red[2][wid] = smu; red[3][wid] = scov; }
    __syncthreads();
    if (tid == 0) {
        s1 = red[0][0] + red[0][1] + red[0][2] + red[0][3];
        s2 = red[1][0] + red[1][1] + red[1][2] + red[1][3];
        smu = red[2][0] + red[2][1] + red[2][2] + red[2][3];
        scov = red[3][0] + red[3][1] + red[3][2] + red[3][3];
        float m1m = s1 * (1.f / NS), m2m = s2 * (1.f / NS);
        float mu_diff = smu * (1.f / NS) * (1.f / (float)C);
        float cov_diff = scov / ((float)C * (float)C);
        tab.losspart[(tab.b0 + bl) * 3 + P.lid] = fmaxf(m1m, m2m) + mu_diff + cov_diff;
    }
}

__global__ void out_kernel(const float* __restrict__ lp, float* __restrict__ out)
{
    int t = threadIdx.x;
    if (t < NT) {
        float s = 0.f;
        for (int k = 0; k < BSZ; ++k)
            for (int l = 0; l < 3; ++l)
                s += lp[(k * NT + t) * 3 + l];
        out[t] = s * (1.f / BSZ);
    }
}

static inline size_t alignup(size_t v) { return (v + 255) & ~(size_t)255; }

static size_t layer_bytes(int C, int nb) {
    int nchunk = C / CCH;
    int tc = C / 128, ntri = tc * (tc + 1) / 2;
    size_t szZ = alignup((size_t)NS * C * 2);
    size_t szP = alignup((size_t)nchunk * NS * 4);
    return (size_t)nb * (4 * szZ + 2 * szP + 4 * alignup(NS * 4)
                         + 2 * alignup(C * 4) + alignup(ntri * 4));
}

static char* fill_layer(LayerP& P, char* p, int C, int n, int nb, int lid,
                        const float* g, const float* t, const int* ix, const int* iy) {
    P.g = g; P.t = t; P.ix = ix; P.iy = iy;
    P.C = C; P.n = n; P.lid = lid;
    P.nchunk = C / CCH;
    int tc = C / 128;
    P.ntri = tc * (tc + 1) / 2;
    size_t szZ = alignup((size_t)NS * C * 2);
    size_t szP = alignup((size_t)P.nchunk * NS * 4);
    P.Xt = (u16*)p;  p += nb * szZ;
    P.Yt = (u16*)p;  p += nb * szZ;
    P.Xn = (u16*)p;  p += nb * szZ;
    P.Yn = (u16*)p;  p += nb * szZ;
    P.xp = (float*)p; p += nb * szP;
    P.yp = (float*)p; p += nb * szP;
    P.xnv = (float*)p; p += nb * alignup(NS * 4);
    P.ynv = (float*)p; p += nb * alignup(NS * 4);
    P.m1u = (unsigned*)p; p += nb * alignup(NS * 4);
    P.m2u = (unsigned*)p; p += nb * alignup(NS * 4);
    P.sx = (float*)p; p += nb * alignup(C * 4);
    P.sy = (float*)p; p += nb * alignup(C * 4);
    P.cov = (float*)p; p += nb * alignup(P.ntri * 4);
    return p;
}

static void launch_group(const Tab& tab, hipStream_t stream) {
    int sumC = 0, sumNchunk = 0, sumC64 = 0, sumNtri = 0;
    for (int l = 0; l < tab.nl; ++l) {
        sumC += tab.L[l].C;
        sumNchunk += tab.L[l].nchunk;
        sumC64 += tab.L[l].C / 64;
        sumNtri += tab.L[l].ntri;
    }
    int nb = tab.nb;
    gather_t<<<dim3(sumC, nb), 256, 0, stream>>>(tab);
    colnorm_part<<<dim3(NS / 512, sumNchunk, nb), 256, 0, stream>>>(tab);
    colnorm_reduce<<<dim3(NS / 256, tab.nl, nb), 256, 0, stream>>>(tab);
    transpose_norm<<<dim3(sumC64, NS / 64, nb * 2), 256, 0, stream>>>(tab);
    cross_mfma<<<dim3(NS / 128, NS / 128, tab.nl * nb), 256, 0, stream>>>(tab);
    cov_mfma<<<dim3(sumNtri, nb), 256, 0, stream>>>(tab);
    finalize_kernel<<<dim3(tab.nl, nb), 256, 0, stream>>>(tab);
}

extern "C" void kernel_launch(void* const* d_in, const int* in_sizes, int n_in,
                              void* d_out, int out_size, void* d_ws, size_t ws_size,
                              hipStream_t stream)
{
    const float* tp[3] = {(const float*)d_in[0], (const float*)d_in[4], (const float*)d_in[8]};
    const float* gp[3] = {(const float*)d_in[1], (const float*)d_in[5], (const float*)d_in[9]};
    const int* ixp[3]  = {(const int*)d_in[2], (const int*)d_in[6], (const int*)d_in[10]};
    const int* iyp[3]  = {(const int*)d_in[3], (const int*)d_in[7], (const int*)d_in[11]};
    const int Cs[3] = {128, 256, 512};
    const int Sp[3] = {128, 64, 32};

    float* out = (float*)d_out;
    char* ws = (char*)d_ws;
    float* losspart = (float*)ws;           // BB*3 floats
    size_t base = alignup(BB * 3 * 4);
    size_t avail = (ws_size > base) ? ws_size - base : 0;

    size_t need_all = 0;
    for (int l = 0; l < 3; ++l) need_all += layer_bytes(Cs[l], BB);

    if (avail >= need_all) {
        // Fused path: one 8-kernel chain for everything.
        Tab tab;
        tab.nl = 3; tab.nb = BB; tab.b0 = 0; tab.losspart = losspart;
        char* p = ws + base;
        for (int l = 0; l < 3; ++l)
            p = fill_layer(tab.L[l], p, Cs[l], Sp[l] * Sp[l], BB, l,
                           gp[l], tp[l], ixp[l], iyp[l]);
        launch_group(tab, stream);
    } else {
        // Fallback: per-layer, batch-chunked (same kernels, 1-layer table).
        for (int l = 0; l < 3; ++l) {
            size_t per_b = layer_bytes(Cs[l], 1);
            int G = (int)(avail / per_b);
            if (G > BB) G = BB;
            if (G < 1) G = 1;
            for (int b0 = 0; b0 < BB; b0 += G) {
                int nb = (BB - b0 < G) ? (BB - b0) : G;
                Tab tab;
                tab.nl = 1; tab.nb = nb; tab.b0 = b0; tab.losspart = losspart;
                fill_layer(tab.L[0], ws + base, Cs[l], Sp[l] * Sp[l], nb, l,
                           gp[l], tp[l], ixp[l], iyp[l]);
                launch_group(tab, stream);
            }
        }
    }
    out_kernel<<<1, 64, 0, stream>>>(losspart, out);
}

// Round 5
// 230.500 us; speedup vs baseline: 6.0495x; 1.1024x over previous
//
#include <hip/hip_runtime.h>
#include <math.h>

#define NT 4
#define BSZ 4
#define BB 16
#define NS 1024
#define GCH 4096   // floats staged in LDS per chunk (16 KB)
#define MAXL 3

typedef unsigned short u16;
typedef __attribute__((ext_vector_type(8))) short bf16x8;
typedef __attribute__((ext_vector_type(4))) float f32x4;

struct LayerP {
    const float *g, *t;
    const int *ix, *iy;
    u16 *Xt, *Yt, *Xs, *Ys;          // c-major gathers; s-major transposes
    float *xp, *yp;                  // per-(C/64)-tile partial sum-of-squares
    float *rxn, *ryn;                // reciprocal sample norms
    float *sx, *sy;                  // per-channel sums
    unsigned *m1u, *m2u;
    float *cov;
    int C, n, nchunk, ntri, lid;
};
struct Tab {
    LayerP L[MAXL];
    int nl, nb, b0, ysh;
    float* losspart;   // [BB][3]
};

__device__ __forceinline__ unsigned fenc(float f) {
    unsigned u = __float_as_uint(f);
    return (u & 0x80000000u) ? ~u : (u | 0x80000000u);
}
__device__ __forceinline__ float fdec(unsigned u) {
    unsigned v = (u & 0x80000000u) ? (u & 0x7FFFFFFFu) : ~u;
    return __uint_as_float(v);
}
__device__ __forceinline__ u16 f2bf(float f) {  // RNE
    unsigned u = __float_as_uint(f);
    unsigned r = u + 0x7FFFu + ((u >> 16) & 1u);
    return (u16)(r >> 16);
}
__device__ __forceinline__ float bf2f(u16 h) {
    return __uint_as_float((unsigned)h << 16);
}

// X gather: stream g-row through LDS chunks (coalesced), gather samples from LDS.
// Also fused per-channel sum.
__global__ __launch_bounds__(256) void gather_x(Tab tab)
{
    int x = blockIdx.x, l = 0;
    while (l < MAXL - 1 && x >= tab.L[l].C) { x -= tab.L[l].C; ++l; }
    const LayerP P = tab.L[l];
    int c = x, bl = blockIdx.y, bg = tab.b0 + bl;
    int tid = threadIdx.x;
    const float* __restrict__ grow = P.g + ((size_t)bg * P.C + c) * P.n;
    const int* __restrict__ ixr = P.ix + bg * NS;
    __shared__ __align__(16) float buf[GCH];
    __shared__ float red[4];
    int px[4];
    float xv[4] = {0.f, 0.f, 0.f, 0.f};
    #pragma unroll
    for (int r = 0; r < 4; ++r) px[r] = ixr[tid + r * 256];
    int n = P.n;
    for (int lo = 0; lo < n; lo += GCH) {
        int sz = min(GCH, n - lo);
        __syncthreads();
        for (int i = tid * 4; i < sz; i += 1024)
            *(float4*)&buf[i] = *(const float4*)&grow[lo + i];
        __syncthreads();
        #pragma unroll
        for (int r = 0; r < 4; ++r) {
            int rel = px[r] - lo;
            if ((unsigned)rel < (unsigned)sz) xv[r] = buf[rel];
        }
    }
    u16* __restrict__ xo = P.Xt + ((size_t)bl * P.C + c) * NS;
    float ax = 0.f;
    #pragma unroll
    for (int r = 0; r < 4; ++r) {
        u16 hb = f2bf(xv[r]);
        xo[tid + r * 256] = hb;
        ax += bf2f(hb);
    }
    for (int o = 32; o > 0; o >>= 1) ax += __shfl_down(ax, o);
    int wid = tid >> 6, lane = tid & 63;
    if (lane == 0) red[wid] = ax;
    __syncthreads();
    if (tid == 0) P.sx[bl * P.C + c] = red[0] + red[1] + red[2] + red[3];
}

// Y gather: one block per (c, target) stages the t-row once and gathers for the
// ysh batch replicas that share it (ysh=4 fused, 1 fallback).
__global__ __launch_bounds__(256) void gather_y(Tab tab)
{
    int x = blockIdx.x, l = 0;
    while (l < MAXL - 1 && x >= tab.L[l].C) { x -= tab.L[l].C; ++l; }
    const LayerP P = tab.L[l];
    int c = x, grp = blockIdx.y;
    int tid = threadIdx.x;
    int nk, tgt, bls[4];
    if (tab.ysh == NT) {
        nk = 4; tgt = grp;
        #pragma unroll
        for (int k = 0; k < 4; ++k) bls[k] = grp + NT * k;
    } else {
        nk = 1; bls[0] = grp; tgt = (tab.b0 + grp) % NT;
        bls[1] = bls[2] = bls[3] = 0;
    }
    const float* __restrict__ trow = P.t + ((size_t)tgt * P.C + c) * P.n;
    __shared__ __align__(16) float buf[GCH];
    __shared__ float red[4][4];
    int py[4][4];
    float yv[4][4];
    #pragma unroll
    for (int k = 0; k < 4; ++k) {
        if (k < nk) {
            const int* iyr = P.iy + (tab.b0 + bls[k]) * NS;
            #pragma unroll
            for (int r = 0; r < 4; ++r) { py[k][r] = iyr[tid + r * 256]; yv[k][r] = 0.f; }
        }
    }
    int n = P.n;
    for (int lo = 0; lo < n; lo += GCH) {
        int sz = min(GCH, n - lo);
        __syncthreads();
        for (int i = tid * 4; i < sz; i += 1024)
            *(float4*)&buf[i] = *(const float4*)&trow[lo + i];
        __syncthreads();
        #pragma unroll
        for (int k = 0; k < 4; ++k)
            if (k < nk) {
                #pragma unroll
                for (int r = 0; r < 4; ++r) {
                    int rel = py[k][r] - lo;
                    if ((unsigned)rel < (unsigned)sz) yv[k][r] = buf[rel];
                }
            }
    }
    int wid = tid >> 6, lane = tid & 63;
    #pragma unroll
    for (int k = 0; k < 4; ++k) {
        if (k >= nk) break;
        u16* __restrict__ yo = P.Yt + ((size_t)bls[k] * P.C + c) * NS;
        float ay = 0.f;
        #pragma unroll
        for (int r = 0; r < 4; ++r) {
            u16 hb = f2bf(yv[k][r]);
            yo[tid + r * 256] = hb;
            ay += bf2f(hb);
        }
        for (int o = 32; o > 0; o >>= 1) ay += __shfl_down(ay, o);
        if (lane == 0) red[k][wid] = ay;
    }
    __syncthreads();
    if (tid < nk)
        P.sy[bls[tid] * P.C + c] = red[tid][0] + red[tid][1] + red[tid][2] + red[tid][3];
}

// 64x64 plain transpose (c-major -> s-major) + fused per-sample sum-of-squares
// partials per 64-channel tile.
__global__ void transpose_k(Tab tab)
{
    int x = blockIdx.x, l = 0;
    while (l < MAXL - 1 && x >= tab.L[l].C / 64) { x -= tab.L[l].C / 64; ++l; }
    const LayerP P = tab.L[l];
    int z = blockIdx.z;
    int bl = z >> 1, which = z & 1;
    const u16* __restrict__ Zt = which ? P.Yt : P.Xt;
    u16* __restrict__ Zs = which ? P.Ys : P.Xs;
    float* __restrict__ zp = which ? P.yp : P.xp;
    int C = P.C;
    int ctile = x;
    int c0 = ctile * 64, s0 = blockIdx.y * 64;
    __shared__ __align__(16) u16 T[64][72];
    int tid = threadIdx.x;
    #pragma unroll
    for (int rep = 0; rep < 2; ++rep) {
        int q = tid + rep * 256;
        int rr = q >> 3, seg = q & 7;
        *(float4*)&T[rr][seg * 8] =
            *(const float4*)&Zt[((size_t)bl * C + c0 + rr) * NS + s0 + seg * 8];
    }
    __syncthreads();
    #pragma unroll
    for (int rep = 0; rep < 2; ++rep) {
        int q = tid + rep * 256;
        int sr = q >> 3, cs = q & 7;
        __align__(16) u16 tmp[8];
        float p = 0.f;
        #pragma unroll
        for (int e = 0; e < 8; ++e) {
            u16 h = T[cs * 8 + e][sr];
            tmp[e] = h;
            float v = bf2f(h);
            p = fmaf(v, v, p);
        }
        *(float4*)&Zs[((size_t)bl * NS + s0 + sr) * C + c0 + cs * 8] = *(float4*)tmp;
        p += __shfl_xor(p, 1);
        p += __shfl_xor(p, 2);
        p += __shfl_xor(p, 4);
        if (cs == 0)
            zp[((size_t)bl * P.nchunk + ctile) * NS + s0 + sr] = p;
    }
}

// Reduce sq-partials -> reciprocal norms; init min buffers.
__global__ void colnorm_reduce(Tab tab)
{
    const LayerP P = tab.L[blockIdx.y];
    int bl = blockIdx.z;
    int s = blockIdx.x * 256 + threadIdx.x;
    float ax = 0.f, ay = 0.f;
    for (int k = 0; k < P.nchunk; ++k) {
        size_t o = ((size_t)bl * P.nchunk + k) * NS + s;
        ax += P.xp[o];
        ay += P.yp[o];
    }
    P.rxn[bl * NS + s] = rsqrtf(ax);
    P.ryn[bl * NS + s] = rsqrtf(ay);
    P.m1u[bl * NS + s] = 0xFFFFFFFFu;
    P.m2u[bl * NS + s] = 0xFFFFFFFFu;
}

// 128x128 MFMA tile of cos-dist = 1 - (X.Y^T)*rx_i*ry_j; fused row/col min epilogue.
__global__ __launch_bounds__(256) void cross_mfma(Tab tab)
{
    int z = blockIdx.z;
    int l = z / tab.nb, bl = z - l * tab.nb;
    const LayerP P = tab.L[l];
    int C = P.C;
    int i0 = blockIdx.x * 128, j0 = blockIdx.y * 128;
    __shared__ __align__(16) u16 As[128][40], Bs[128][40];
    int tid = threadIdx.x;
    int w = tid >> 6, lane = tid & 63;
    int wr = w >> 1, wc = w & 1;
    int q = lane >> 4, r = lane & 15;
    const u16* __restrict__ Xb = P.Xs + ((size_t)bl * NS + i0) * C;
    const u16* __restrict__ Yb = P.Ys + ((size_t)bl * NS + j0) * C;
    f32x4 acc[4][4];
    #pragma unroll
    for (int m = 0; m < 4; ++m)
        #pragma unroll
        for (int nn = 0; nn < 4; ++nn) acc[m][nn] = (f32x4){0.f, 0.f, 0.f, 0.f};

    for (int kk = 0; kk < C; kk += 32) {
        __syncthreads();
        #pragma unroll
        for (int rep = 0; rep < 2; ++rep) {
            int qid = tid + rep * 256;
            int row = qid >> 2, seg = qid & 3;
            size_t off = (size_t)row * C + kk + seg * 8;
            *(float4*)&As[row][seg * 8] = *(const float4*)&Xb[off];
            *(float4*)&Bs[row][seg * 8] = *(const float4*)&Yb[off];
        }
        __syncthreads();
        bf16x8 a[4], b[4];
        #pragma unroll
        for (int m = 0; m < 4; ++m)
            a[m] = *(const bf16x8*)&As[wr * 64 + m * 16 + r][q * 8];
        #pragma unroll
        for (int nn = 0; nn < 4; ++nn)
            b[nn] = *(const bf16x8*)&Bs[wc * 64 + nn * 16 + r][q * 8];
        #pragma unroll
        for (int m = 0; m < 4; ++m)
            #pragma unroll
            for (int nn = 0; nn < 4; ++nn)
                acc[m][nn] = __builtin_amdgcn_mfma_f32_16x16x32_bf16(a[m], b[nn], acc[m][nn], 0, 0, 0);
    }

    float rxl[4][4], ryl[4];
    #pragma unroll
    for (int m = 0; m < 4; ++m)
        #pragma unroll
        for (int reg = 0; reg < 4; ++reg)
            rxl[m][reg] = P.rxn[bl * NS + i0 + wr * 64 + m * 16 + q * 4 + reg];
    #pragma unroll
    for (int nn = 0; nn < 4; ++nn)
        ryl[nn] = P.ryn[bl * NS + j0 + wc * 64 + nn * 16 + r];

    float rm[4][4], cm[4];
    #pragma unroll
    for (int m = 0; m < 4; ++m)
        #pragma unroll
        for (int reg = 0; reg < 4; ++reg) rm[m][reg] = 1e30f;
    #pragma unroll
    for (int nn = 0; nn < 4; ++nn) cm[nn] = 1e30f;
    #pragma unroll
    for (int m = 0; m < 4; ++m)
        #pragma unroll
        for (int nn = 0; nn < 4; ++nn)
            #pragma unroll
            for (int reg = 0; reg < 4; ++reg) {
                float d = 1.f - acc[m][nn][reg] * rxl[m][reg] * ryl[nn];
                rm[m][reg] = fminf(rm[m][reg], d);
                cm[nn] = fminf(cm[nn], d);
            }
    #pragma unroll
    for (int m = 0; m < 4; ++m)
        #pragma unroll
        for (int reg = 0; reg < 4; ++reg) {
            float v = rm[m][reg];
            v = fminf(v, __shfl_xor(v, 1));
            v = fminf(v, __shfl_xor(v, 2));
            v = fminf(v, __shfl_xor(v, 4));
            v = fminf(v, __shfl_xor(v, 8));
            rm[m][reg] = v;
        }
    if (r == 0) {
        #pragma unroll
        for (int m = 0; m < 4; ++m)
            #pragma unroll
            for (int reg = 0; reg < 4; ++reg) {
                int i = i0 + wr * 64 + m * 16 + q * 4 + reg;
                atomicMin(&P.m2u[bl * NS + i], fenc(rm[m][reg]));
            }
    }
    #pragma unroll
    for (int nn = 0; nn < 4; ++nn) {
        float v = cm[nn];
        v = fminf(v, __shfl_xor(v, 16));
        v = fminf(v, __shfl_xor(v, 32));
        cm[nn] = v;
    }
    if (q == 0) {
        #pragma unroll
        for (int nn = 0; nn < 4; ++nn) {
            int j = j0 + wc * 64 + nn * 16 + r;
            atomicMin(&P.m1u[bl * NS + j], fenc(cm[nn]));
        }
    }
}

// Dual 128x128 MFMA tile of Sxx/Syy; upper-triangle tiles, off-diag weighted 2x.
__global__ __launch_bounds__(256) void cov_mfma(Tab tab)
{
    int x = blockIdx.x, l = 0;
    while (l < MAXL - 1 && x >= tab.L[l].ntri) { x -= tab.L[l].ntri; ++l; }
    const LayerP P = tab.L[l];
    int u = x;
    int bl = blockIdx.y;
    int C = P.C;
    int ty = 0;
    while ((ty + 1) * (ty + 2) / 2 <= u) ++ty;
    int tx = u - ty * (ty + 1) / 2;
    int c0 = ty * 128, d0 = tx * 128;
    float wgt = (tx == ty) ? 1.f : 2.f;

    __shared__ __align__(16) u16 As[128][40], Bs[128][40], Cs2[128][40], Ds[128][40];
    int tid = threadIdx.x;
    int w = tid >> 6, lane = tid & 63;
    int wr = w >> 1, wc = w & 1;
    int q = lane >> 4, r = lane & 15;
    const u16* __restrict__ Xc = P.Xt + ((size_t)bl * C + c0) * NS;
    const u16* __restrict__ Xd = P.Xt + ((size_t)bl * C + d0) * NS;
    const u16* __restrict__ Yc = P.Yt + ((size_t)bl * C + c0) * NS;
    const u16* __restrict__ Yd = P.Yt + ((size_t)bl * C + d0) * NS;

    f32x4 accX[4][4], accY[4][4];
    #pragma unroll
    for (int m = 0; m < 4; ++m)
        #pragma unroll
        for (int nn = 0; nn < 4; ++nn) {
            accX[m][nn] = (f32x4){0.f, 0.f, 0.f, 0.f};
            accY[m][nn] = (f32x4){0.f, 0.f, 0.f, 0.f};
        }

    for (int ss = 0; ss < NS; ss += 32) {
        __syncthreads();
        #pragma unroll
        for (int rep = 0; rep < 2; ++rep) {
            int qid = tid + rep * 256;
            int row = qid >> 2, seg = qid & 3;
            size_t off = (size_t)row * NS + ss + seg * 8;
            *(float4*)&As[row][seg * 8]  = *(const float4*)&Xc[off];
            *(float4*)&Bs[row][seg * 8]  = *(const float4*)&Xd[off];
            *(float4*)&Cs2[row][seg * 8] = *(const float4*)&Yc[off];
            *(float4*)&Ds[row][seg * 8]  = *(const float4*)&Yd[off];
        }
        __syncthreads();
        {
            bf16x8 a[4], b[4];
            #pragma unroll
            for (int m = 0; m < 4; ++m) a[m] = *(const bf16x8*)&As[wr * 64 + m * 16 + r][q * 8];
            #pragma unroll
            for (int nn = 0; nn < 4; ++nn) b[nn] = *(const bf16x8*)&Bs[wc * 64 + nn * 16 + r][q * 8];
            #pragma unroll
            for (int m = 0; m < 4; ++m)
                #pragma unroll
                for (int nn = 0; nn < 4; ++nn)
                    accX[m][nn] = __builtin_amdgcn_mfma_f32_16x16x32_bf16(a[m], b[nn], accX[m][nn], 0, 0, 0);
        }
        {
            bf16x8 a[4], b[4];
            #pragma unroll
            for (int m = 0; m < 4; ++m) a[m] = *(const bf16x8*)&Cs2[wr * 64 + m * 16 + r][q * 8];
            #pragma unroll
            for (int nn = 0; nn < 4; ++nn) b[nn] = *(const bf16x8*)&Ds[wc * 64 + nn * 16 + r][q * 8];
            #pragma unroll
            for (int m = 0; m < 4; ++m)
                #pragma unroll
                for (int nn = 0; nn < 4; ++nn)
                    accY[m][nn] = __builtin_amdgcn_mfma_f32_16x16x32_bf16(a[m], b[nn], accY[m][nn], 0, 0, 0);
        }
    }

    float scxv[4][4], scyv[4][4], sdxv[4], sdyv[4];
    #pragma unroll
    for (int m = 0; m < 4; ++m)
        #pragma unroll
        for (int reg = 0; reg < 4; ++reg) {
            int c = c0 + wr * 64 + m * 16 + q * 4 + reg;
            scxv[m][reg] = P.sx[bl * C + c];
            scyv[m][reg] = P.sy[bl * C + c];
        }
    #pragma unroll
    for (int nn = 0; nn < 4; ++nn) {
        int d = d0 + wc * 64 + nn * 16 + r;
        sdxv[nn] = P.sx[bl * C + d];
        sdyv[nn] = P.sy[bl * C + d];
    }
    const float invNS = 1.f / NS, invNSm1 = 1.f / (NS - 1);
    float tsum = 0.f;
    #pragma unroll
    for (int m = 0; m < 4; ++m)
        #pragma unroll
        for (int nn = 0; nn < 4; ++nn)
            #pragma unroll
            for (int reg = 0; reg < 4; ++reg) {
                float cx = (accX[m][nn][reg] - scxv[m][reg] * sdxv[nn] * invNS) * invNSm1;
                float cy = (accY[m][nn][reg] - scyv[m][reg] * sdyv[nn] * invNS) * invNSm1;
                tsum += fabsf(cx - cy);
            }
    tsum *= wgt;
    __shared__ float redc[4];
    for (int o = 32; o > 0; o >>= 1) tsum += __shfl_down(tsum, o);
    if (lane == 0) redc[w] = tsum;
    __syncthreads();
    if (tid == 0)
        P.cov[(size_t)bl * P.ntri + u] = redc[0] + redc[1] + redc[2] + redc[3];
}

__global__ void finalize_kernel(Tab tab)
{
    const LayerP P = tab.L[blockIdx.x];
    int bl = blockIdx.y;
    int tid = threadIdx.x;
    int C = P.C;
    float s1 = 0.f, s2 = 0.f, smu = 0.f, scov = 0.f;
    for (int s = tid; s < NS; s += 256) {
        s1 += fdec(P.m1u[bl * NS + s]);
        s2 += fdec(P.m2u[bl * NS + s]);
    }
    for (int c = tid; c < C; c += 256) smu += fabsf(P.sx[bl * C + c] - P.sy[bl * C + c]);
    for (int i = tid; i < P.ntri; i += 256) scov += P.cov[(size_t)bl * P.ntri + i];
    __shared__ float red[4][4];
    for (int o = 32; o > 0; o >>= 1) {
        s1 += __shfl_down(s1, o);
        s2 += __shfl_down(s2, o);
        smu += __shfl_down(smu, o);
        scov += __shfl_down(scov, o);
    }
    int wid = tid >> 6, lane = tid & 63;
    if (lane == 0) { red[0][wid] = s1; red[1][wid] = s2; red[2][wid] = smu; red[3][wid] = scov; }
    __syncthreads();
    if (tid == 0) {
        s1 = red[0][0] + red[0][1] + red[0][2] + red[0][3];
        s2 = red[1][0] + red[1][1] + red[1][2] + red[1][3];
        smu = red[2][0] + red[2][1] + red[2][2] + red[2][3];
        scov = red[3][0] + red[3][1] + red[3][2] + red[3][3];
        float m1m = s1 * (1.f / NS), m2m = s2 * (1.f / NS);
        float mu_diff = smu * (1.f / NS) * (1.f / (float)C);
        float cov_diff = scov / ((float)C * (float)C);
        tab.losspart[(tab.b0 + bl) * 3 + P.lid] = fmaxf(m1m, m2m) + mu_diff + cov_diff;
    }
}

__global__ void out_kernel(const float* __restrict__ lp, float* __restrict__ out)
{
    int t = threadIdx.x;
    if (t < NT) {
        float s = 0.f;
        for (int k = 0; k < BSZ; ++k)
            for (int l = 0; l < 3; ++l)
                s += lp[(k * NT + t) * 3 + l];
        out[t] = s * (1.f / BSZ);
    }
}

static inline size_t alignup(size_t v) { return (v + 255) & ~(size_t)255; }

static size_t layer_bytes(int C, int nb) {
    int nchunk = C / 64;
    int tc = C / 128, ntri = tc * (tc + 1) / 2;
    size_t szZ = alignup((size_t)NS * C * 2);
    size_t szP = alignup((size_t)nchunk * NS * 4);
    return (size_t)nb * (4 * szZ + 2 * szP + 4 * alignup(NS * 4)
                         + 2 * alignup(C * 4) + alignup(ntri * 4));
}

static char* fill_layer(LayerP& P, char* p, int C, int n, int nb, int lid,
                        const float* g, const float* t, const int* ix, const int* iy) {
    P.g = g; P.t = t; P.ix = ix; P.iy = iy;
    P.C = C; P.n = n; P.lid = lid;
    P.nchunk = C / 64;
    int tc = C / 128;
    P.ntri = tc * (tc + 1) / 2;
    size_t szZ = alignup((size_t)NS * C * 2);
    size_t szP = alignup((size_t)P.nchunk * NS * 4);
    P.Xt = (u16*)p;  p += nb * szZ;
    P.Yt = (u16*)p;  p += nb * szZ;
    P.Xs = (u16*)p;  p += nb * szZ;
    P.Ys = (u16*)p;  p += nb * szZ;
    P.xp = (float*)p; p += nb * szP;
    P.yp = (float*)p; p += nb * szP;
    P.rxn = (float*)p; p += nb * alignup(NS * 4);
    P.ryn = (float*)p; p += nb * alignup(NS * 4);
    P.m1u = (unsigned*)p; p += nb * alignup(NS * 4);
    P.m2u = (unsigned*)p; p += nb * alignup(NS * 4);
    P.sx = (float*)p; p += nb * alignup(C * 4);
    P.sy = (float*)p; p += nb * alignup(C * 4);
    P.cov = (float*)p; p += nb * alignup(P.ntri * 4);
    return p;
}

static void launch_group(const Tab& tab, hipStream_t stream) {
    int sumC = 0, sumC64 = 0, sumNtri = 0;
    for (int l = 0; l < tab.nl; ++l) {
        sumC += tab.L[l].C;
        sumC64 += tab.L[l].C / 64;
        sumNtri += tab.L[l].ntri;
    }
    int nb = tab.nb;
    int ygrid = (tab.ysh == NT) ? NT : nb;
    gather_x<<<dim3(sumC, nb), 256, 0, stream>>>(tab);
    gather_y<<<dim3(sumC, ygrid), 256, 0, stream>>>(tab);
    transpose_k<<<dim3(sumC64, NS / 64, nb * 2), 256, 0, stream>>>(tab);
    colnorm_reduce<<<dim3(NS / 256, tab.nl, nb), 256, 0, stream>>>(tab);
    cross_mfma<<<dim3(NS / 128, NS / 128, tab.nl * nb), 256, 0, stream>>>(tab);
    cov_mfma<<<dim3(sumNtri, nb), 256, 0, stream>>>(tab);
    finalize_kernel<<<dim3(tab.nl, nb), 256, 0, stream>>>(tab);
}

extern "C" void kernel_launch(void* const* d_in, const int* in_sizes, int n_in,
                              void* d_out, int out_size, void* d_ws, size_t ws_size,
                              hipStream_t stream)
{
    const float* tp[3] = {(const float*)d_in[0], (const float*)d_in[4], (const float*)d_in[8]};
    const float* gp[3] = {(const float*)d_in[1], (const float*)d_in[5], (const float*)d_in[9]};
    const int* ixp[3]  = {(const int*)d_in[2], (const int*)d_in[6], (const int*)d_in[10]};
    const int* iyp[3]  = {(const int*)d_in[3], (const int*)d_in[7], (const int*)d_in[11]};
    const int Cs[3] = {128, 256, 512};
    const int Sp[3] = {128, 64, 32};

    float* out = (float*)d_out;
    char* ws = (char*)d_ws;
    float* losspart = (float*)ws;           // BB*3 floats
    size_t base = alignup(BB * 3 * 4);
    size_t avail = (ws_size > base) ? ws_size - base : 0;

    size_t need_all = 0;
    for (int l = 0; l < 3; ++l) need_all += layer_bytes(Cs[l], BB);

    if (avail >= need_all) {
        Tab tab;
        tab.nl = 3; tab.nb = BB; tab.b0 = 0; tab.ysh = NT; tab.losspart = losspart;
        char* p = ws + base;
        for (int l = 0; l < 3; ++l)
            p = fill_layer(tab.L[l], p, Cs[l], Sp[l] * Sp[l], BB, l,
                           gp[l], tp[l], ixp[l], iyp[l]);
        launch_group(tab, stream);
    } else {
        for (int l = 0; l < 3; ++l) {
            size_t per_b = layer_bytes(Cs[l], 1);
            int G = (int)(avail / per_b);
            if (G > BB) G = BB;
            if (G < 1) G = 1;
            for (int b0 = 0; b0 < BB; b0 += G) {
                int nb = (BB - b0 < G) ? (BB - b0) : G;
                Tab tab;
                tab.nl = 1; tab.nb = nb; tab.b0 = b0; tab.ysh = 1; tab.losspart = losspart;
                fill_layer(tab.L[0], ws + base, Cs[l], Sp[l] * Sp[l], nb, l,
                           gp[l], tp[l], ixp[l], iyp[l]);
                launch_group(tab, stream);
            }
        }
    }
    out_kernel<<<1, 64, 0, stream>>>(losspart, out);
}

// Round 6
// 226.924 us; speedup vs baseline: 6.1449x; 1.0158x over previous
//
#include <hip/hip_runtime.h>
#include <math.h>

#define NT 4
#define BSZ 4
#define BB 16
#define NS 1024
#define GCH 2048   // floats per LDS chunk (8 KB); double-buffered = 16 KB
#define MAXL 3

typedef unsigned short u16;
typedef __attribute__((ext_vector_type(8))) short bf16x8;
typedef __attribute__((ext_vector_type(4))) float f32x4;

struct LayerP {
    const float *g, *t;
    const int *ix, *iy;
    u16 *Xt, *Yt, *Xs, *Ys;          // c-major gathers; s-major transposes
    float *xp, *yp;                  // per-(C/64)-tile partial sum-of-squares
    float *rxn, *ryn;                // reciprocal sample norms
    float *sx, *sy;                  // per-channel sums
    unsigned *m1u, *m2u;
    float *cov;
    int C, n, nchunk, ntri, lid;
};
struct Tab {
    LayerP L[MAXL];
    int nl, nb, b0, ysh;
    float* losspart;   // [BB][3]
};

__device__ __forceinline__ unsigned fenc(float f) {
    unsigned u = __float_as_uint(f);
    return (u & 0x80000000u) ? ~u : (u | 0x80000000u);
}
__device__ __forceinline__ float fdec(unsigned u) {
    unsigned v = (u & 0x80000000u) ? (u & 0x7FFFFFFFu) : ~u;
    return __uint_as_float(v);
}
__device__ __forceinline__ u16 f2bf(float f) {  // RNE
    unsigned u = __float_as_uint(f);
    unsigned r = u + 0x7FFFu + ((u >> 16) & 1u);
    return (u16)(r >> 16);
}
__device__ __forceinline__ float bf2f(u16 h) {
    return __uint_as_float((unsigned)h << 16);
}

// Stage one GCH-float chunk: explicit regs force >=2 loads in flight.
__device__ __forceinline__ void stage_load(const float* __restrict__ src, int lo, int n,
                                           int tid, float4& a, float4& b) {
    int i0 = lo + tid * 4;
    int i1 = i0 + 1024;
    a = (i0 < n) ? *(const float4*)&src[i0] : make_float4(0.f, 0.f, 0.f, 0.f);
    b = (i1 < n) ? *(const float4*)&src[i1] : make_float4(0.f, 0.f, 0.f, 0.f);
}
__device__ __forceinline__ void stage_write(float* dst, int tid, const float4& a, const float4& b) {
    *(float4*)&dst[tid * 4] = a;
    *(float4*)&dst[tid * 4 + 1024] = b;
}
// Barrier that does NOT drain in-flight global loads (only LDS ops).
__device__ __forceinline__ void lds_barrier() {
    asm volatile("s_waitcnt lgkmcnt(0)" ::: "memory");
    __builtin_amdgcn_s_barrier();
}

// X gather: double-buffered LDS streaming of the g-row, gather samples from LDS.
// Fused per-channel sum.
__global__ __launch_bounds__(256) void gather_x(Tab tab)
{
    int x = blockIdx.x, l = 0;
    while (l < MAXL - 1 && x >= tab.L[l].C) { x -= tab.L[l].C; ++l; }
    const LayerP P = tab.L[l];
    int c = x, bl = blockIdx.y, bg = tab.b0 + bl;
    int tid = threadIdx.x;
    const float* __restrict__ grow = P.g + ((size_t)bg * P.C + c) * P.n;
    const int* __restrict__ ixr = P.ix + bg * NS;
    __shared__ __align__(16) float buf[2][GCH];
    __shared__ float red[4];
    int px[4];
    float xv[4] = {0.f, 0.f, 0.f, 0.f};
    #pragma unroll
    for (int r = 0; r < 4; ++r) px[r] = ixr[tid + r * 256];
    int n = P.n;
    int nch = (n + GCH - 1) / GCH;
    float4 a, b;
    stage_load(grow, 0, n, tid, a, b);
    stage_write(buf[0], tid, a, b);
    if (nch > 1) stage_load(grow, GCH, n, tid, a, b);
    lds_barrier();
    for (int ch = 0; ch < nch; ++ch) {
        int lo = ch * GCH;
        int sz = min(GCH, n - lo);
        #pragma unroll
        for (int r = 0; r < 4; ++r) {
            int rel = px[r] - lo;
            if ((unsigned)rel < (unsigned)sz) xv[r] = buf[ch & 1][rel];
        }
        if (ch + 1 < nch) {
            stage_write(buf[(ch + 1) & 1], tid, a, b);
            if (ch + 2 < nch) stage_load(grow, (ch + 2) * GCH, n, tid, a, b);
            lds_barrier();
        }
    }
    u16* __restrict__ xo = P.Xt + ((size_t)bl * P.C + c) * NS;
    float ax = 0.f;
    #pragma unroll
    for (int r = 0; r < 4; ++r) {
        u16 hb = f2bf(xv[r]);
        xo[tid + r * 256] = hb;
        ax += bf2f(hb);
    }
    for (int o = 32; o > 0; o >>= 1) ax += __shfl_down(ax, o);
    int wid = tid >> 6, lane = tid & 63;
    if (lane == 0) red[wid] = ax;
    __syncthreads();
    if (tid == 0) P.sx[bl * P.C + c] = red[0] + red[1] + red[2] + red[3];
}

// Y gather: one block per (c, target); stages the t-row once, gathers for the
// ysh batch replicas sharing it (ysh=4 fused path, 1 fallback).
__global__ __launch_bounds__(256) void gather_y(Tab tab)
{
    int x = blockIdx.x, l = 0;
    while (l < MAXL - 1 && x >= tab.L[l].C) { x -= tab.L[l].C; ++l; }
    const LayerP P = tab.L[l];
    int c = x, grp = blockIdx.y;
    int tid = threadIdx.x;
    int nk, tgt, bls[4];
    if (tab.ysh == NT) {
        nk = 4; tgt = grp;
        #pragma unroll
        for (int k = 0; k < 4; ++k) bls[k] = grp + NT * k;
    } else {
        nk = 1; bls[0] = grp; tgt = (tab.b0 + grp) % NT;
        bls[1] = bls[2] = bls[3] = 0;
    }
    const float* __restrict__ trow = P.t + ((size_t)tgt * P.C + c) * P.n;
    __shared__ __align__(16) float buf[2][GCH];
    __shared__ float red[4][4];
    int py[4][4];
    float yv[4][4];
    #pragma unroll
    for (int k = 0; k < 4; ++k) {
        if (k < nk) {
            const int* iyr = P.iy + (tab.b0 + bls[k]) * NS;
            #pragma unroll
            for (int r = 0; r < 4; ++r) { py[k][r] = iyr[tid + r * 256]; yv[k][r] = 0.f; }
        }
    }
    int n = P.n;
    int nch = (n + GCH - 1) / GCH;
    float4 a, b;
    stage_load(trow, 0, n, tid, a, b);
    stage_write(buf[0], tid, a, b);
    if (nch > 1) stage_load(trow, GCH, n, tid, a, b);
    lds_barrier();
    for (int ch = 0; ch < nch; ++ch) {
        int lo = ch * GCH;
        int sz = min(GCH, n - lo);
        #pragma unroll
        for (int k = 0; k < 4; ++k)
            if (k < nk) {
                #pragma unroll
                for (int r = 0; r < 4; ++r) {
                    int rel = py[k][r] - lo;
                    if ((unsigned)rel < (unsigned)sz) yv[k][r] = buf[ch & 1][rel];
                }
            }
        if (ch + 1 < nch) {
            stage_write(buf[(ch + 1) & 1], tid, a, b);
            if (ch + 2 < nch) stage_load(trow, (ch + 2) * GCH, n, tid, a, b);
            lds_barrier();
        }
    }
    int wid = tid >> 6, lane = tid & 63;
    #pragma unroll
    for (int k = 0; k < 4; ++k) {
        if (k >= nk) break;
        u16* __restrict__ yo = P.Yt + ((size_t)bls[k] * P.C + c) * NS;
        float ay = 0.f;
        #pragma unroll
        for (int r = 0; r < 4; ++r) {
            u16 hb = f2bf(yv[k][r]);
            yo[tid + r * 256] = hb;
            ay += bf2f(hb);
        }
        for (int o = 32; o > 0; o >>= 1) ay += __shfl_down(ay, o);
        if (lane == 0) red[k][wid] = ay;
    }
    __syncthreads();
    if (tid < nk)
        P.sy[bls[tid] * P.C + c] = red[tid][0] + red[tid][1] + red[tid][2] + red[tid][3];
}

// 64x64 plain transpose (c-major -> s-major) + fused per-sample sum-of-squares
// partials per 64-channel tile.
__global__ void transpose_k(Tab tab)
{
    int x = blockIdx.x, l = 0;
    while (l < MAXL - 1 && x >= tab.L[l].C / 64) { x -= tab.L[l].C / 64; ++l; }
    const LayerP P = tab.L[l];
    int z = blockIdx.z;
    int bl = z >> 1, which = z & 1;
    const u16* __restrict__ Zt = which ? P.Yt : P.Xt;
    u16* __restrict__ Zs = which ? P.Ys : P.Xs;
    float* __restrict__ zp = which ? P.yp : P.xp;
    int C = P.C;
    int ctile = x;
    int c0 = ctile * 64, s0 = blockIdx.y * 64;
    __shared__ __align__(16) u16 T[64][72];
    int tid = threadIdx.x;
    #pragma unroll
    for (int rep = 0; rep < 2; ++rep) {
        int q = tid + rep * 256;
        int rr = q >> 3, seg = q & 7;
        *(float4*)&T[rr][seg * 8] =
            *(const float4*)&Zt[((size_t)bl * C + c0 + rr) * NS + s0 + seg * 8];
    }
    __syncthreads();
    #pragma unroll
    for (int rep = 0; rep < 2; ++rep) {
        int q = tid + rep * 256;
        int sr = q >> 3, cs = q & 7;
        __align__(16) u16 tmp[8];
        float p = 0.f;
        #pragma unroll
        for (int e = 0; e < 8; ++e) {
            u16 h = T[cs * 8 + e][sr];
            tmp[e] = h;
            float v = bf2f(h);
            p = fmaf(v, v, p);
        }
        *(float4*)&Zs[((size_t)bl * NS + s0 + sr) * C + c0 + cs * 8] = *(float4*)tmp;
        p += __shfl_xor(p, 1);
        p += __shfl_xor(p, 2);
        p += __shfl_xor(p, 4);
        if (cs == 0)
            zp[((size_t)bl * P.nchunk + ctile) * NS + s0 + sr] = p;
    }
}

// Reduce sq-partials -> reciprocal norms; init min buffers.
__global__ void colnorm_reduce(Tab tab)
{
    const LayerP P = tab.L[blockIdx.y];
    int bl = blockIdx.z;
    int s = blockIdx.x * 256 + threadIdx.x;
    float ax = 0.f, ay = 0.f;
    for (int k = 0; k < P.nchunk; ++k) {
        size_t o = ((size_t)bl * P.nchunk + k) * NS + s;
        ax += P.xp[o];
        ay += P.yp[o];
    }
    P.rxn[bl * NS + s] = rsqrtf(ax);
    P.ryn[bl * NS + s] = rsqrtf(ay);
    P.m1u[bl * NS + s] = 0xFFFFFFFFu;
    P.m2u[bl * NS + s] = 0xFFFFFFFFu;
}

// 128x128 MFMA tile of cos-dist = 1 - (X.Y^T)*rx_i*ry_j; fused row/col min epilogue.
__global__ __launch_bounds__(256) void cross_mfma(Tab tab)
{
    int z = blockIdx.z;
    int l = z / tab.nb, bl = z - l * tab.nb;
    const LayerP P = tab.L[l];
    int C = P.C;
    int i0 = blockIdx.x * 128, j0 = blockIdx.y * 128;
    __shared__ __align__(16) u16 As[128][40], Bs[128][40];
    int tid = threadIdx.x;
    int w = tid >> 6, lane = tid & 63;
    int wr = w >> 1, wc = w & 1;
    int q = lane >> 4, r = lane & 15;
    const u16* __restrict__ Xb = P.Xs + ((size_t)bl * NS + i0) * C;
    const u16* __restrict__ Yb = P.Ys + ((size_t)bl * NS + j0) * C;
    f32x4 acc[4][4];
    #pragma unroll
    for (int m = 0; m < 4; ++m)
        #pragma unroll
        for (int nn = 0; nn < 4; ++nn) acc[m][nn] = (f32x4){0.f, 0.f, 0.f, 0.f};

    for (int kk = 0; kk < C; kk += 32) {
        __syncthreads();
        #pragma unroll
        for (int rep = 0; rep < 2; ++rep) {
            int qid = tid + rep * 256;
            int row = qid >> 2, seg = qid & 3;
            size_t off = (size_t)row * C + kk + seg * 8;
            *(float4*)&As[row][seg * 8] = *(const float4*)&Xb[off];
            *(float4*)&Bs[row][seg * 8] = *(const float4*)&Yb[off];
        }
        __syncthreads();
        bf16x8 a[4], b[4];
        #pragma unroll
        for (int m = 0; m < 4; ++m)
            a[m] = *(const bf16x8*)&As[wr * 64 + m * 16 + r][q * 8];
        #pragma unroll
        for (int nn = 0; nn < 4; ++nn)
            b[nn] = *(const bf16x8*)&Bs[wc * 64 + nn * 16 + r][q * 8];
        #pragma unroll
        for (int m = 0; m < 4; ++m)
            #pragma unroll
            for (int nn = 0; nn < 4; ++nn)
                acc[m][nn] = __builtin_amdgcn_mfma_f32_16x16x32_bf16(a[m], b[nn], acc[m][nn], 0, 0, 0);
    }

    float rxl[4][4], ryl[4];
    #pragma unroll
    for (int m = 0; m < 4; ++m)
        #pragma unroll
        for (int reg = 0; reg < 4; ++reg)
            rxl[m][reg] = P.rxn[bl * NS + i0 + wr * 64 + m * 16 + q * 4 + reg];
    #pragma unroll
    for (int nn = 0; nn < 4; ++nn)
        ryl[nn] = P.ryn[bl * NS + j0 + wc * 64 + nn * 16 + r];

    float rm[4][4], cm[4];
    #pragma unroll
    for (int m = 0; m < 4; ++m)
        #pragma unroll
        for (int reg = 0; reg < 4; ++reg) rm[m][reg] = 1e30f;
    #pragma unroll
    for (int nn = 0; nn < 4; ++nn) cm[nn] = 1e30f;
    #pragma unroll
    for (int m = 0; m < 4; ++m)
        #pragma unroll
        for (int nn = 0; nn < 4; ++nn)
            #pragma unroll
            for (int reg = 0; reg < 4; ++reg) {
                float d = 1.f - acc[m][nn][reg] * rxl[m][reg] * ryl[nn];
                rm[m][reg] = fminf(rm[m][reg], d);
                cm[nn] = fminf(cm[nn], d);
            }
    #pragma unroll
    for (int m = 0; m < 4; ++m)
        #pragma unroll
        for (int reg = 0; reg < 4; ++reg) {
            float v = rm[m][reg];
            v = fminf(v, __shfl_xor(v, 1));
            v = fminf(v, __shfl_xor(v, 2));
            v = fminf(v, __shfl_xor(v, 4));
            v = fminf(v, __shfl_xor(v, 8));
            rm[m][reg] = v;
        }
    if (r == 0) {
        #pragma unroll
        for (int m = 0; m < 4; ++m)
            #pragma unroll
            for (int reg = 0; reg < 4; ++reg) {
                int i = i0 + wr * 64 + m * 16 + q * 4 + reg;
                atomicMin(&P.m2u[bl * NS + i], fenc(rm[m][reg]));
            }
    }
    #pragma unroll
    for (int nn = 0; nn < 4; ++nn) {
        float v = cm[nn];
        v = fminf(v, __shfl_xor(v, 16));
        v = fminf(v, __shfl_xor(v, 32));
        cm[nn] = v;
    }
    if (q == 0) {
        #pragma unroll
        for (int nn = 0; nn < 4; ++nn) {
            int j = j0 + wc * 64 + nn * 16 + r;
            atomicMin(&P.m1u[bl * NS + j], fenc(cm[nn]));
        }
    }
}

// Dual 128x128 MFMA tile of Sxx/Syy; upper-triangle tiles, off-diag weighted 2x.
__global__ __launch_bounds__(256) void cov_mfma(Tab tab)
{
    int x = blockIdx.x, l = 0;
    while (l < MAXL - 1 && x >= tab.L[l].ntri) { x -= tab.L[l].ntri; ++l; }
    const LayerP P = tab.L[l];
    int u = x;
    int bl = blockIdx.y;
    int C = P.C;
    int ty = 0;
    while ((ty + 1) * (ty + 2) / 2 <= u) ++ty;
    int tx = u - ty * (ty + 1) / 2;
    int c0 = ty * 128, d0 = tx * 128;
    float wgt = (tx == ty) ? 1.f : 2.f;

    __shared__ __align__(16) u16 As[128][40], Bs[128][40], Cs2[128][40], Ds[128][40];
    int tid = threadIdx.x;
    int w = tid >> 6, lane = tid & 63;
    int wr = w >> 1, wc = w & 1;
    int q = lane >> 4, r = lane & 15;
    const u16* __restrict__ Xc = P.Xt + ((size_t)bl * C + c0) * NS;
    const u16* __restrict__ Xd = P.Xt + ((size_t)bl * C + d0) * NS;
    const u16* __restrict__ Yc = P.Yt + ((size_t)bl * C + c0) * NS;
    const u16* __restrict__ Yd = P.Yt + ((size_t)bl * C + d0) * NS;

    f32x4 accX[4][4], accY[4][4];
    #pragma unroll
    for (int m = 0; m < 4; ++m)
        #pragma unroll
        for (int nn = 0; nn < 4; ++nn) {
            accX[m][nn] = (f32x4){0.f, 0.f, 0.f, 0.f};
            accY[m][nn] = (f32x4){0.f, 0.f, 0.f, 0.f};
        }

    for (int ss = 0; ss < NS; ss += 32) {
        __syncthreads();
        #pragma unroll
        for (int rep = 0; rep < 2; ++rep) {
            int qid = tid + rep * 256;
            int row = qid >> 2, seg = qid & 3;
            size_t off = (size_t)row * NS + ss + seg * 8;
            *(float4*)&As[row][seg * 8]  = *(const float4*)&Xc[off];
            *(float4*)&Bs[row][seg * 8]  = *(const float4*)&Xd[off];
            *(float4*)&Cs2[row][seg * 8] = *(const float4*)&Yc[off];
            *(float4*)&Ds[row][seg * 8]  = *(const float4*)&Yd[off];
        }
        __syncthreads();
        {
            bf16x8 a[4], b[4];
            #pragma unroll
            for (int m = 0; m < 4; ++m) a[m] = *(const bf16x8*)&As[wr * 64 + m * 16 + r][q * 8];
            #pragma unroll
            for (int nn = 0; nn < 4; ++nn) b[nn] = *(const bf16x8*)&Bs[wc * 64 + nn * 16 + r][q * 8];
            #pragma unroll
            for (int m = 0; m < 4; ++m)
                #pragma unroll
                for (int nn = 0; nn < 4; ++nn)
                    accX[m][nn] = __builtin_amdgcn_mfma_f32_16x16x32_bf16(a[m], b[nn], accX[m][nn], 0, 0, 0);
        }
        {
            bf16x8 a[4], b[4];
            #pragma unroll
            for (int m = 0; m < 4; ++m) a[m] = *(const bf16x8*)&Cs2[wr * 64 + m * 16 + r][q * 8];
            #pragma unroll
            for (int nn = 0; nn < 4; ++nn) b[nn] = *(const bf16x8*)&Ds[wc * 64 + nn * 16 + r][q * 8];
            #pragma unroll
            for (int m = 0; m < 4; ++m)
                #pragma unroll
                for (int nn = 0; nn < 4; ++nn)
                    accY[m][nn] = __builtin_amdgcn_mfma_f32_16x16x32_bf16(a[m], b[nn], accY[m][nn], 0, 0, 0);
        }
    }

    float scxv[4][4], scyv[4][4], sdxv[4], sdyv[4];
    #pragma unroll
    for (int m = 0; m < 4; ++m)
        #pragma unroll
        for (int reg = 0; reg < 4; ++reg) {
            int c = c0 + wr * 64 + m * 16 + q * 4 + reg;
            scxv[m][reg] = P.sx[bl * C + c];
            scyv[m][reg] = P.sy[bl * C + c];
        }
    #pragma unroll
    for (int nn = 0; nn < 4; ++nn) {
        int d = d0 + wc * 64 + nn * 16 + r;
        sdxv[nn] = P.sx[bl * C + d];
        sdyv[nn] = P.sy[bl * C + d];
    }
    const float invNS = 1.f / NS, invNSm1 = 1.f / (NS - 1);
    float tsum = 0.f;
    #pragma unroll
    for (int m = 0; m < 4; ++m)
        #pragma unroll
        for (int nn = 0; nn < 4; ++nn)
            #pragma unroll
            for (int reg = 0; reg < 4; ++reg) {
                float cx = (accX[m][nn][reg] - scxv[m][reg] * sdxv[nn] * invNS) * invNSm1;
                float cy = (accY[m][nn][reg] - scyv[m][reg] * sdyv[nn] * invNS) * invNSm1;
                tsum += fabsf(cx - cy);
            }
    tsum *= wgt;
    __shared__ float redc[4];
    for (int o = 32; o > 0; o >>= 1) tsum += __shfl_down(tsum, o);
    if (lane == 0) redc[w] = tsum;
    __syncthreads();
    if (tid == 0)
        P.cov[(size_t)bl * P.ntri + u] = redc[0] + redc[1] + redc[2] + redc[3];
}

__global__ void finalize_kernel(Tab tab)
{
    const LayerP P = tab.L[blockIdx.x];
    int bl = blockIdx.y;
    int tid = threadIdx.x;
    int C = P.C;
    float s1 = 0.f, s2 = 0.f, smu = 0.f, scov = 0.f;
    for (int s = tid; s < NS; s += 256) {
        s1 += fdec(P.m1u[bl * NS + s]);
        s2 += fdec(P.m2u[bl * NS + s]);
    }
    for (int c = tid; c < C; c += 256) smu += fabsf(P.sx[bl * C + c] - P.sy[bl * C + c]);
    for (int i = tid; i < P.ntri; i += 256) scov += P.cov[(size_t)bl * P.ntri + i];
    __shared__ float red[4][4];
    for (int o = 32; o > 0; o >>= 1) {
        s1 += __shfl_down(s1, o);
        s2 += __shfl_down(s2, o);
        smu += __shfl_down(smu, o);
        scov += __shfl_down(scov, o);
    }
    int wid = tid >> 6, lane = tid & 63;
    if (lane == 0) { red[0][wid] = s1; red[1][wid] = s2; red[2][wid] = smu; red[3][wid] = scov; }
    __syncthreads();
    if (tid == 0) {
        s1 = red[0][0] + red[0][1] + red[0][2] + red[0][3];
        s2 = red[1][0] + red[1][1] + red[1][2] + red[1][3];
        smu = red[2][0] + red[2][1] + red[2][2] + red[2][3];
        scov = red[3][0] + red[3][1] + red[3][2] + red[3][3];
        float m1m = s1 * (1.f / NS), m2m = s2 * (1.f / NS);
        float mu_diff = smu * (1.f / NS) * (1.f / (float)C);
        float cov_diff = scov / ((float)C * (float)C);
        tab.losspart[(tab.b0 + bl) * 3 + P.lid] = fmaxf(m1m, m2m) + mu_diff + cov_diff;
    }
}

__global__ void out_kernel(const float* __restrict__ lp, float* __restrict__ out)
{
    int t = threadIdx.x;
    if (t < NT) {
        float s = 0.f;
        for (int k = 0; k < BSZ; ++k)
            for (int l = 0; l < 3; ++l)
                s += lp[(k * NT + t) * 3 + l];
        out[t] = s * (1.f / BSZ);
    }
}

static inline size_t alignup(size_t v) { return (v + 255) & ~(size_t)255; }

static size_t layer_bytes(int C, int nb) {
    int nchunk = C / 64;
    int tc = C / 128, ntri = tc * (tc + 1) / 2;
    size_t szZ = alignup((size_t)NS * C * 2);
    size_t szP = alignup((size_t)nchunk * NS * 4);
    return (size_t)nb * (4 * szZ + 2 * szP + 4 * alignup(NS * 4)
                         + 2 * alignup(C * 4) + alignup(ntri * 4));
}

static char* fill_layer(LayerP& P, char* p, int C, int n, int nb, int lid,
                        const float* g, const float* t, const int* ix, const int* iy) {
    P.g = g; P.t = t; P.ix = ix; P.iy = iy;
    P.C = C; P.n = n; P.lid = lid;
    P.nchunk = C / 64;
    int tc = C / 128;
    P.ntri = tc * (tc + 1) / 2;
    size_t szZ = alignup((size_t)NS * C * 2);
    size_t szP = alignup((size_t)P.nchunk * NS * 4);
    P.Xt = (u16*)p;  p += nb * szZ;
    P.Yt = (u16*)p;  p += nb * szZ;
    P.Xs = (u16*)p;  p += nb * szZ;
    P.Ys = (u16*)p;  p += nb * szZ;
    P.xp = (float*)p; p += nb * szP;
    P.yp = (float*)p; p += nb * szP;
    P.rxn = (float*)p; p += nb * alignup(NS * 4);
    P.ryn = (float*)p; p += nb * alignup(NS * 4);
    P.m1u = (unsigned*)p; p += nb * alignup(NS * 4);
    P.m2u = (unsigned*)p; p += nb * alignup(NS * 4);
    P.sx = (float*)p; p += nb * alignup(C * 4);
    P.sy = (float*)p; p += nb * alignup(C * 4);
    P.cov = (float*)p; p += nb * alignup(P.ntri * 4);
    return p;
}

static void launch_group(const Tab& tab, hipStream_t stream) {
    int sumC = 0, sumC64 = 0, sumNtri = 0;
    for (int l = 0; l < tab.nl; ++l) {
        sumC += tab.L[l].C;
        sumC64 += tab.L[l].C / 64;
        sumNtri += tab.L[l].ntri;
    }
    int nb = tab.nb;
    int ygrid = (tab.ysh == NT) ? NT : nb;
    gather_x<<<dim3(sumC, nb), 256, 0, stream>>>(tab);
    gather_y<<<dim3(sumC, ygrid), 256, 0, stream>>>(tab);
    transpose_k<<<dim3(sumC64, NS / 64, nb * 2), 256, 0, stream>>>(tab);
    colnorm_reduce<<<dim3(NS / 256, tab.nl, nb), 256, 0, stream>>>(tab);
    cross_mfma<<<dim3(NS / 128, NS / 128, tab.nl * nb), 256, 0, stream>>>(tab);
    cov_mfma<<<dim3(sumNtri, nb), 256, 0, stream>>>(tab);
    finalize_kernel<<<dim3(tab.nl, nb), 256, 0, stream>>>(tab);
}

extern "C" void kernel_launch(void* const* d_in, const int* in_sizes, int n_in,
                              void* d_out, int out_size, void* d_ws, size_t ws_size,
                              hipStream_t stream)
{
    const float* tp[3] = {(const float*)d_in[0], (const float*)d_in[4], (const float*)d_in[8]};
    const float* gp[3] = {(const float*)d_in[1], (const float*)d_in[5], (const float*)d_in[9]};
    const int* ixp[3]  = {(const int*)d_in[2], (const int*)d_in[6], (const int*)d_in[10]};
    const int* iyp[3]  = {(const int*)d_in[3], (const int*)d_in[7], (const int*)d_in[11]};
    const int Cs[3] = {128, 256, 512};
    const int Sp[3] = {128, 64, 32};

    float* out = (float*)d_out;
    char* ws = (char*)d_ws;
    float* losspart = (float*)ws;           // BB*3 floats
    size_t base = alignup(BB * 3 * 4);
    size_t avail = (ws_size > base) ? ws_size - base : 0;

    size_t need_all = 0;
    for (int l = 0; l < 3; ++l) need_all += layer_bytes(Cs[l], BB);

    if (avail >= need_all) {
        Tab tab;
        tab.nl = 3; tab.nb = BB; tab.b0 = 0; tab.ysh = NT; tab.losspart = losspart;
        char* p = ws + base;
        for (int l = 0; l < 3; ++l)
            p = fill_layer(tab.L[l], p, Cs[l], Sp[l] * Sp[l], BB, l,
                           gp[l], tp[l], ixp[l], iyp[l]);
        launch_group(tab, stream);
    } else {
        for (int l = 0; l < 3; ++l) {
            size_t per_b = layer_bytes(Cs[l], 1);
            int G = (int)(avail / per_b);
            if (G > BB) G = BB;
            if (G < 1) G = 1;
            for (int b0 = 0; b0 < BB; b0 += G) {
                int nb = (BB - b0 < G) ? (BB - b0) : G;
                Tab tab;
                tab.nl = 1; tab.nb = nb; tab.b0 = b0; tab.ysh = 1; tab.losspart = losspart;
                fill_layer(tab.L[0], ws + base, Cs[l], Sp[l] * Sp[l], nb, l,
                           gp[l], tp[l], ixp[l], iyp[l]);
                launch_group(tab, stream);
            }
        }
    }
    out_kernel<<<1, 64, 0, stream>>>(losspart, out);
}